// Round 1
// baseline (678.290 us; speedup 1.0000x reference)
//
#include <hip/hip_runtime.h>

typedef unsigned short u16;
typedef unsigned int u32;
typedef __attribute__((ext_vector_type(4))) float f32x4;
typedef __attribute__((ext_vector_type(8))) short short8;
typedef __attribute__((ext_vector_type(4))) u32 u32x4;
typedef __attribute__((ext_vector_type(4))) u16 u16x4;

#define BB 4
#define LL 2048
#define DD 1024
#define HH 8
#define DHH 128

__device__ __forceinline__ u16 f2b(float f) {
  u32 u = __builtin_bit_cast(u32, f);
  u += 0x7fffu + ((u >> 16) & 1u);
  return (u16)(u >> 16);
}
__device__ __forceinline__ float b2f(u16 h) {
  u32 u = ((u32)h) << 16;
  return __builtin_bit_cast(float, u);
}

// ---------------- elementwise fp32 -> bf16 ----------------
__global__ __launch_bounds__(256) void cvt_k(const float* __restrict__ X,
                                             u16* __restrict__ Xb, long n) {
  long i = ((long)blockIdx.x * 256 + threadIdx.x) * 4;
  if (i >= n) return;
  f32x4 v = *(const f32x4*)(X + i);
  u16x4 o;
#pragma unroll
  for (int k = 0; k < 4; k++) o[k] = f2b(v[k]);
  *(u16x4*)(Xb + i) = o;
}

// ---------------- 1024x1024 fp32 -> bf16 transpose (WT[n][k] = W[k][n]) ----
__global__ __launch_bounds__(256) void tr_k(const float* __restrict__ W,
                                            u16* __restrict__ WT) {
  __shared__ float tile[32][33];
  const int bx = blockIdx.x, by = blockIdx.y;
  const int tx = threadIdx.x & 31, ty = threadIdx.x >> 5;
#pragma unroll
  for (int i = 0; i < 4; i++)
    tile[ty + i * 8][tx] =
        W[(long)(by * 32 + ty + i * 8) * 1024 + bx * 32 + tx];
  __syncthreads();
#pragma unroll
  for (int i = 0; i < 4; i++)
    WT[(long)(bx * 32 + ty + i * 8) * 1024 + by * 32 + tx] =
        f2b(tile[tx][ty + i * 8]);
}

// ---------------- 128x128x32 bf16 MFMA GEMM: C = A[M,K] @ W, W given as WT[N,K]
// epilogue: (acc + bias[col]) * scale, optional relu, store bf16 or fp32
template <bool RELU, bool OUTB>
__global__ __launch_bounds__(256, 2) void gemm_k(
    const u16* __restrict__ A, const u16* __restrict__ BT,
    const float* __restrict__ bias, float scale, float* __restrict__ Cf,
    u16* __restrict__ Cb, int M, int N, int K) {
  __shared__ u16 As[128][40];  // stride 80B = 5*16 -> aligned b128, ~2-way
  __shared__ u16 Bs[128][40];
  const int t = threadIdx.x;
  const int l = t & 63, w = t >> 6;
  const int lr = l & 15, lg = l >> 4;
  const int wr = (w >> 1) * 64, wc = (w & 1) * 64;
  const long bm = (long)blockIdx.y * 128, bn = (long)blockIdx.x * 128;
  const int srow = t >> 1, scol = (t & 1) * 16;
  const u16* Ap = A + (bm + srow) * K + scol;
  const u16* Bp = BT + (bn + srow) * K + scol;
  f32x4 acc[4][4] = {};
  for (int k0 = 0; k0 < K; k0 += 32) {
    *(u32x4*)&As[srow][scol] = *(const u32x4*)(Ap + k0);
    *(u32x4*)&As[srow][scol + 8] = *(const u32x4*)(Ap + k0 + 8);
    *(u32x4*)&Bs[srow][scol] = *(const u32x4*)(Bp + k0);
    *(u32x4*)&Bs[srow][scol + 8] = *(const u32x4*)(Bp + k0 + 8);
    __syncthreads();
    short8 af[4], bf[4];
#pragma unroll
    for (int i = 0; i < 4; i++)
      af[i] = *(const short8*)&As[wr + i * 16 + lr][lg * 8];
#pragma unroll
    for (int i = 0; i < 4; i++)
      bf[i] = *(const short8*)&Bs[wc + i * 16 + lr][lg * 8];
#pragma unroll
    for (int i = 0; i < 4; i++)
#pragma unroll
      for (int j = 0; j < 4; j++)
        acc[i][j] = __builtin_amdgcn_mfma_f32_16x16x32_bf16(af[i], bf[j],
                                                            acc[i][j], 0, 0, 0);
    __syncthreads();
  }
#pragma unroll
  for (int i = 0; i < 4; i++)
#pragma unroll
    for (int j = 0; j < 4; j++) {
      long col = bn + wc + j * 16 + lr;
      float bv = bias[col];
#pragma unroll
      for (int r = 0; r < 4; r++) {
        long row = bm + wr + i * 16 + lg * 4 + r;
        float v2 = (acc[i][j][r] + bv) * scale;
        if (RELU) v2 = fmaxf(v2, 0.f);
        if (OUTB)
          Cb[row * N + col] = f2b(v2);
        else
          Cf[row * N + col] = v2;
      }
    }
}

// ---------------- flash attention: grid (L/64, B*H), 4 waves x 16 q rows ----
__global__ __launch_bounds__(256, 2) void flash_k(const u16* __restrict__ Q,
                                                  const u16* __restrict__ Kb,
                                                  const u16* __restrict__ Vb,
                                                  float* __restrict__ ctx) {
  __shared__ u16 Ks[64][136];     // row-major K tile, stride 272B (17*16)
  __shared__ u16 Vt[128][72];     // transposed V tile [d][kv], stride 144B
  __shared__ u16 Pw[4][16][72];   // per-wave P relayout buffer
  const int t = threadIdx.x;
  const int l = t & 63, w = t >> 6;
  const int lr = l & 15, lg = l >> 4;
  const int bh = blockIdx.y;
  const int b = bh >> 3, h = bh & 7;
  const long base = ((long)b * LL) * DD + h * DHH;
  const int q0 = blockIdx.x * 64;

  short8 qf[4];
  {
    const u16* qp = Q + base + (long)(q0 + w * 16 + lr) * DD + lg * 8;
#pragma unroll
    for (int c = 0; c < 4; c++) qf[c] = *(const short8*)(qp + c * 32);
  }
  f32x4 oacc[8] = {};
  float mprev[4] = {-1e30f, -1e30f, -1e30f, -1e30f};
  float lsum[4] = {0.f, 0.f, 0.f, 0.f};

  const int ksr = t >> 4;        // 0..15
  const int ksc = (t & 15) * 8;  // 0..120
  for (int kb = 0; kb < LL; kb += 64) {
#pragma unroll
    for (int i = 0; i < 4; i++) {
      int row = i * 16 + ksr;
      *(u32x4*)&Ks[row][ksc] =
          *(const u32x4*)(Kb + base + (long)(kb + row) * DD + ksc);
    }
#pragma unroll
    for (int i = 0; i < 4; i++) {
      int c = w * 4 + i;  // d-chunk 0..15
      short8 vv = *(const short8*)(Vb + base + (long)(kb + l) * DD + c * 8);
#pragma unroll
      for (int j = 0; j < 8; j++) Vt[c * 8 + j][l] = (u16)vv[j];
    }
    __syncthreads();

    f32x4 s[4] = {};
#pragma unroll
    for (int jc = 0; jc < 4; jc++)
#pragma unroll
      for (int c = 0; c < 4; c++) {
        short8 kf = *(const short8*)&Ks[jc * 16 + lr][c * 32 + lg * 8];
        s[jc] =
            __builtin_amdgcn_mfma_f32_16x16x32_bf16(qf[c], kf, s[jc], 0, 0, 0);
      }

    float mnew[4], alpha[4], rs[4];
#pragma unroll
    for (int r = 0; r < 4; r++) {
      float mx = fmaxf(fmaxf(s[0][r], s[1][r]), fmaxf(s[2][r], s[3][r]));
      mx = fmaxf(mx, __shfl_xor(mx, 1, 64));
      mx = fmaxf(mx, __shfl_xor(mx, 2, 64));
      mx = fmaxf(mx, __shfl_xor(mx, 4, 64));
      mx = fmaxf(mx, __shfl_xor(mx, 8, 64));
      mnew[r] = fmaxf(mprev[r], mx);
      alpha[r] = __expf(mprev[r] - mnew[r]);
      mprev[r] = mnew[r];
      rs[r] = 0.f;
    }
#pragma unroll
    for (int jc = 0; jc < 4; jc++)
#pragma unroll
      for (int r = 0; r < 4; r++) {
        float p = __expf(s[jc][r] - mnew[r]);
        rs[r] += p;
        Pw[w][lg * 4 + r][jc * 16 + lr] = f2b(p);
      }
#pragma unroll
    for (int r = 0; r < 4; r++) {
      rs[r] += __shfl_xor(rs[r], 1, 64);
      rs[r] += __shfl_xor(rs[r], 2, 64);
      rs[r] += __shfl_xor(rs[r], 4, 64);
      rs[r] += __shfl_xor(rs[r], 8, 64);
      lsum[r] = lsum[r] * alpha[r] + rs[r];
    }
#pragma unroll
    for (int d8 = 0; d8 < 8; d8++)
#pragma unroll
      for (int r = 0; r < 4; r++) oacc[d8][r] *= alpha[r];

#pragma unroll
    for (int kk = 0; kk < 2; kk++) {
      short8 pf = *(const short8*)&Pw[w][lr][kk * 32 + lg * 8];
#pragma unroll
      for (int d8 = 0; d8 < 8; d8++) {
        short8 vf = *(const short8*)&Vt[d8 * 16 + lr][kk * 32 + lg * 8];
        oacc[d8] =
            __builtin_amdgcn_mfma_f32_16x16x32_bf16(pf, vf, oacc[d8], 0, 0, 0);
      }
    }
    __syncthreads();
  }
#pragma unroll
  for (int r = 0; r < 4; r++) {
    float inv = 1.f / lsum[r];
    float* cp = ctx + base + (long)(q0 + w * 16 + lg * 4 + r) * DD;
#pragma unroll
    for (int d8 = 0; d8 < 8; d8++) cp[d8 * 16 + lr] = oacc[d8][r] * inv;
  }
}

// ---------------- residual + layernorm; writes fp32 and/or bf16 ----------
__global__ __launch_bounds__(256) void ln_k(const float* __restrict__ X,
                                            const float* __restrict__ R,
                                            const float* __restrict__ gamma,
                                            const float* __restrict__ beta,
                                            float* __restrict__ Hf,
                                            u16* __restrict__ Hb) {
  const int row = blockIdx.x, t = threadIdx.x;
  const long off = (long)row * DD + t * 4;
  f32x4 v = *(const f32x4*)(X + off);
  f32x4 rv = *(const f32x4*)(R + off);
#pragma unroll
  for (int i = 0; i < 4; i++) v[i] += rv[i];
  float s = v[0] + v[1] + v[2] + v[3];
  float q = v[0] * v[0] + v[1] * v[1] + v[2] * v[2] + v[3] * v[3];
#pragma unroll
  for (int m = 32; m >= 1; m >>= 1) {
    s += __shfl_xor(s, m, 64);
    q += __shfl_xor(q, m, 64);
  }
  __shared__ float red[8];
  if ((t & 63) == 0) {
    red[t >> 6] = s;
    red[4 + (t >> 6)] = q;
  }
  __syncthreads();
  s = red[0] + red[1] + red[2] + red[3];
  q = red[4] + red[5] + red[6] + red[7];
  const float mean = s * (1.f / 1024.f);
  const float var = q * (1.f / 1024.f) - mean * mean;
  const float rstd = rsqrtf(var + 1e-12f);
  f32x4 g = *(const f32x4*)(gamma + t * 4);
  f32x4 be = *(const f32x4*)(beta + t * 4);
  f32x4 o;
#pragma unroll
  for (int i = 0; i < 4; i++) o[i] = g[i] * (v[i] - mean) * rstd + be[i];
  if (Hf) *(f32x4*)(Hf + off) = o;
  if (Hb) {
    u16x4 ob;
#pragma unroll
    for (int i = 0; i < 4; i++) ob[i] = f2b(o[i]);
    *(u16x4*)(Hb + off) = ob;
  }
}

// ---------------- c2: row dot wc2 + relu -> cvec[row] ----------------
__global__ __launch_bounds__(256) void c2_k(const u16* __restrict__ C,
                                            const float* __restrict__ wc2,
                                            const float* __restrict__ bc2,
                                            float* __restrict__ cvec) {
  const int row = blockIdx.x, t = threadIdx.x;
  u16x4 cv = *(const u16x4*)(C + (long)row * DD + t * 4);
  f32x4 wv = *(const f32x4*)(wc2 + t * 4);
  float s = b2f(cv[0]) * wv[0] + b2f(cv[1]) * wv[1] + b2f(cv[2]) * wv[2] +
            b2f(cv[3]) * wv[3];
#pragma unroll
  for (int m = 32; m >= 1; m >>= 1) s += __shfl_xor(s, m, 64);
  __shared__ float red[4];
  if ((t & 63) == 0) red[t >> 6] = s;
  __syncthreads();
  if (t == 0)
    cvec[row] = fmaxf(red[0] + red[1] + red[2] + red[3] + bc2[0], 0.f);
}

// ---------------- small [4,Lr]@[Lr,N] GEMM: split-K partials + reduce -----
__global__ __launch_bounds__(256) void smm_part(const float* __restrict__ Cin,
                                                const float* __restrict__ W,
                                                float* __restrict__ P, int Lr,
                                                int N, int SL) {
  const int j = blockIdx.x * 256 + threadIdx.x;
  const int l0 = blockIdx.y * SL;
  float a0 = 0, a1 = 0, a2 = 0, a3 = 0;
  for (int ll = l0; ll < l0 + SL; ll++) {
    float wv = W[(long)ll * N + j];
    a0 += Cin[ll] * wv;
    a1 += Cin[Lr + ll] * wv;
    a2 += Cin[2 * Lr + ll] * wv;
    a3 += Cin[3 * Lr + ll] * wv;
  }
  float* Pp = P + ((long)blockIdx.y * 4) * N + j;
  Pp[0] = a0;
  Pp[N] = a1;
  Pp[2 * N] = a2;
  Pp[3 * N] = a3;
}

template <bool RELU>
__global__ __launch_bounds__(256) void smm_red(const float* __restrict__ P,
                                               const float* __restrict__ bias,
                                               float* __restrict__ Out, int N,
                                               int S) {
  const int j = blockIdx.x * 256 + threadIdx.x;
#pragma unroll
  for (int b = 0; b < 4; b++) {
    float a = 0;
    for (int s = 0; s < S; s++) a += P[((long)s * 4 + b) * N + j];
    a += bias[j];
    if (RELU) a = fmaxf(a, 0.f);
    Out[(long)b * N + j] = a;
  }
}

extern "C" void kernel_launch(void* const* d_in, const int* in_sizes, int n_in,
                              void* d_out, int out_size, void* d_ws,
                              size_t ws_size, hipStream_t stream) {
  (void)in_sizes; (void)n_in; (void)out_size; (void)ws_size;
  const float* x = (const float*)d_in[0];
  const float* wq = (const float*)d_in[1];
  const float* bq = (const float*)d_in[2];
  const float* wk = (const float*)d_in[3];
  const float* bk = (const float*)d_in[4];
  const float* wv = (const float*)d_in[5];
  const float* bv = (const float*)d_in[6];
  const float* gamma = (const float*)d_in[7];
  const float* beta = (const float*)d_in[8];
  const float* wff = (const float*)d_in[9];
  const float* bff = (const float*)d_in[10];
  const float* wc1 = (const float*)d_in[11];
  const float* bc1 = (const float*)d_in[12];
  const float* wc2 = (const float*)d_in[13];
  const float* bc2 = (const float*)d_in[14];
  const float* wl1 = (const float*)d_in[15];
  const float* bl1 = (const float*)d_in[16];
  const float* wl2 = (const float*)d_in[17];
  const float* bl2 = (const float*)d_in[18];

  char* wsp = (char*)d_ws;
  size_t off = 0;
  auto take = [&](size_t bytes) -> char* {
    char* p = wsp + off;
    off += (bytes + 255) & ~(size_t)255;
    return p;
  };
  u16* xb = (u16*)take((size_t)8192 * 1024 * 2);
  u16* wqT = (u16*)take((size_t)1024 * 1024 * 2);
  u16* wkT = (u16*)take((size_t)1024 * 1024 * 2);
  u16* wvT = (u16*)take((size_t)1024 * 1024 * 2);
  u16* wffT = (u16*)take((size_t)1024 * 1024 * 2);
  u16* wc1T = (u16*)take((size_t)1024 * 1024 * 2);
  u16* qb = (u16*)take((size_t)8192 * 1024 * 2);
  u16* kbuf = (u16*)take((size_t)8192 * 1024 * 2);
  u16* vbuf = (u16*)take((size_t)8192 * 1024 * 2);
  float* ctxb = (float*)take((size_t)8192 * 1024 * 4);  // reused as ff
  float* h1f = (float*)take((size_t)8192 * 1024 * 4);
  float* cvec = (float*)take(8192 * 4);
  float* c3 = (float*)take(8192 * 4);
  float* P1 = (float*)take((size_t)16 * 4 * 2048 * 4);
  float* P2 = (float*)take((size_t)16 * 4 * 256 * 4);
  u16* h1b = qb;    // dead after flash
  u16* h2b = kbuf;  // dead after flash
  u16* cb = vbuf;   // dead after flash
  float* ff = ctxb; // dead after LN1

  cvt_k<<<8192, 256, 0, stream>>>(x, xb, (long)8192 * 1024);
  dim3 trg(32, 32);
  tr_k<<<trg, 256, 0, stream>>>(wq, wqT);
  tr_k<<<trg, 256, 0, stream>>>(wk, wkT);
  tr_k<<<trg, 256, 0, stream>>>(wv, wvT);
  tr_k<<<trg, 256, 0, stream>>>(wff, wffT);
  tr_k<<<trg, 256, 0, stream>>>(wc1, wc1T);

  dim3 gg(8, 64);
  gemm_k<false, true><<<gg, 256, 0, stream>>>(
      xb, wqT, bq, 0.08838834764831845f, nullptr, qb, 8192, 1024, 1024);
  gemm_k<false, true><<<gg, 256, 0, stream>>>(xb, wkT, bk, 1.f, nullptr, kbuf,
                                              8192, 1024, 1024);
  gemm_k<false, true><<<gg, 256, 0, stream>>>(xb, wvT, bv, 1.f, nullptr, vbuf,
                                              8192, 1024, 1024);
  flash_k<<<dim3(32, 32), 256, 0, stream>>>(qb, kbuf, vbuf, ctxb);
  ln_k<<<8192, 256, 0, stream>>>(x, ctxb, gamma, beta, h1f, h1b);
  gemm_k<true, false><<<gg, 256, 0, stream>>>(h1b, wffT, bff, 1.f, ff, nullptr,
                                              8192, 1024, 1024);
  ln_k<<<8192, 256, 0, stream>>>(h1f, ff, gamma, beta, nullptr, h2b);
  gemm_k<true, true><<<gg, 256, 0, stream>>>(h2b, wc1T, bc1, 1.f, nullptr, cb,
                                             8192, 1024, 1024);
  c2_k<<<8192, 256, 0, stream>>>(cb, wc2, bc2, cvec);
  smm_part<<<dim3(8, 16), 256, 0, stream>>>(cvec, wl1, P1, 2048, 2048, 128);
  smm_red<true><<<8, 256, 0, stream>>>(P1, bl1, c3, 2048, 16);
  smm_part<<<dim3(1, 16), 256, 0, stream>>>(c3, wl2, P2, 2048, 256, 128);
  smm_red<false><<<1, 256, 0, stream>>>(P2, bl2, (float*)d_out, 256, 16);
}

// Round 2
// 516.280 us; speedup vs baseline: 1.3138x; 1.3138x over previous
//
#include <hip/hip_runtime.h>

typedef unsigned short u16;
typedef unsigned int u32;
typedef __attribute__((ext_vector_type(4))) float f32x4;
typedef __attribute__((ext_vector_type(8))) short short8;
typedef __attribute__((ext_vector_type(4))) u32 u32x4;
typedef __attribute__((ext_vector_type(4))) u16 u16x4;

#define BB 4
#define LL 2048
#define DD 1024
#define HH 8
#define DHH 128

__device__ __forceinline__ u16 f2b(float f) {
  u32 u = __builtin_bit_cast(u32, f);
  u += 0x7fffu + ((u >> 16) & 1u);
  return (u16)(u >> 16);
}
__device__ __forceinline__ float b2f(u16 h) {
  u32 u = ((u32)h) << 16;
  return __builtin_bit_cast(float, u);
}

// ---------------- elementwise fp32 -> bf16 ----------------
__global__ __launch_bounds__(256) void cvt_k(const float* __restrict__ X,
                                             u16* __restrict__ Xb, long n) {
  long i = ((long)blockIdx.x * 256 + threadIdx.x) * 4;
  if (i >= n) return;
  f32x4 v = *(const f32x4*)(X + i);
  u16x4 o;
#pragma unroll
  for (int k = 0; k < 4; k++) o[k] = f2b(v[k]);
  *(u16x4*)(Xb + i) = o;
}

// ---------------- 1024x1024 fp32 -> bf16 transpose (WT[n][k] = W[k][n]) ----
__global__ __launch_bounds__(256) void tr_k(const float* __restrict__ W,
                                            u16* __restrict__ WT) {
  __shared__ float tile[32][33];
  const int bx = blockIdx.x, by = blockIdx.y;
  const int tx = threadIdx.x & 31, ty = threadIdx.x >> 5;
#pragma unroll
  for (int i = 0; i < 4; i++)
    tile[ty + i * 8][tx] =
        W[(long)(by * 32 + ty + i * 8) * 1024 + bx * 32 + tx];
  __syncthreads();
#pragma unroll
  for (int i = 0; i < 4; i++)
    WT[(long)(bx * 32 + ty + i * 8) * 1024 + by * 32 + tx] =
        f2b(tile[tx][ty + i * 8]);
}

// ---------------- 128x128x32 bf16 MFMA GEMM: C = A[M,K] @ W, W given as WT[N,K]
// epilogue: (acc + bias[col]) * scale, optional relu
// OMODE: 0 = fp32 row-major, 1 = bf16 row-major, 2 = bf16 VT layout
//        VT[(b*1024 + col)*2048 + l]  where row = b*2048 + l
template <bool RELU, int OMODE>
__global__ __launch_bounds__(256, 2) void gemm_k(
    const u16* __restrict__ A, const u16* __restrict__ BT,
    const float* __restrict__ bias, float scale, float* __restrict__ Cf,
    u16* __restrict__ Cb, int M, int N, int K) {
  __shared__ u16 As[128][40];  // stride 80B -> aligned b128, ~2-way
  __shared__ u16 Bs[128][40];
  const int t = threadIdx.x;
  const int l = t & 63, w = t >> 6;
  const int lr = l & 15, lg = l >> 4;
  const int wr = (w >> 1) * 64, wc = (w & 1) * 64;
  const long bm = (long)blockIdx.y * 128, bn = (long)blockIdx.x * 128;
  const int srow = t >> 1, scol = (t & 1) * 16;
  const u16* Ap = A + (bm + srow) * K + scol;
  const u16* Bp = BT + (bn + srow) * K + scol;
  f32x4 acc[4][4] = {};
  for (int k0 = 0; k0 < K; k0 += 32) {
    *(u32x4*)&As[srow][scol] = *(const u32x4*)(Ap + k0);
    *(u32x4*)&As[srow][scol + 8] = *(const u32x4*)(Ap + k0 + 8);
    *(u32x4*)&Bs[srow][scol] = *(const u32x4*)(Bp + k0);
    *(u32x4*)&Bs[srow][scol + 8] = *(const u32x4*)(Bp + k0 + 8);
    __syncthreads();
    short8 af[4], bf[4];
#pragma unroll
    for (int i = 0; i < 4; i++)
      af[i] = *(const short8*)&As[wr + i * 16 + lr][lg * 8];
#pragma unroll
    for (int i = 0; i < 4; i++)
      bf[i] = *(const short8*)&Bs[wc + i * 16 + lr][lg * 8];
#pragma unroll
    for (int i = 0; i < 4; i++)
#pragma unroll
      for (int j = 0; j < 4; j++)
        acc[i][j] = __builtin_amdgcn_mfma_f32_16x16x32_bf16(af[i], bf[j],
                                                            acc[i][j], 0, 0, 0);
    __syncthreads();
  }
#pragma unroll
  for (int i = 0; i < 4; i++)
#pragma unroll
    for (int j = 0; j < 4; j++) {
      long col = bn + wc + j * 16 + lr;
      float bv = bias[col];
      if (OMODE == 2) {
        long row0 = bm + wr + i * 16 + lg * 4;
        long b = row0 >> 11, l0 = row0 & 2047;
        u16x4 ov;
#pragma unroll
        for (int r = 0; r < 4; r++) {
          float v2 = (acc[i][j][r] + bv) * scale;
          if (RELU) v2 = fmaxf(v2, 0.f);
          ov[r] = f2b(v2);
        }
        *(u16x4*)(Cb + (b * 1024 + col) * 2048 + l0) = ov;
      } else {
#pragma unroll
        for (int r = 0; r < 4; r++) {
          long row = bm + wr + i * 16 + lg * 4 + r;
          float v2 = (acc[i][j][r] + bv) * scale;
          if (RELU) v2 = fmaxf(v2, 0.f);
          if (OMODE == 1)
            Cb[row * N + col] = f2b(v2);
          else
            Cf[row * N + col] = v2;
        }
      }
    }
}

// ---------------- flash attention v2: grid (L/128, B*H), 8 waves x 16 q rows
__global__ __launch_bounds__(512, 4) void flash_k(const u16* __restrict__ Q,
                                                  const u16* __restrict__ Kb,
                                                  const u16* __restrict__ VT,
                                                  float* __restrict__ ctx) {
  __shared__ u16 Ks[64][136];    // K tile [kv][d]
  __shared__ u16 VTs[128][72];   // V^T tile [d][kv]
  __shared__ u16 Pw[8][16][76];  // per-wave P relayout
  const int t = threadIdx.x;
  const int l = t & 63, w = t >> 6;
  const int lr = l & 15, lg = l >> 4;
  const int bh = blockIdx.y;
  const int b = bh >> 3, h = bh & 7;
  const long kbase = ((long)b * LL) * DD + h * DHH;
  const long vtbase = ((long)(b * 8 + h) * DHH) * LL;
  const int q0 = blockIdx.x * 128;

  short8 qf[4];
  {
    const u16* qp = Q + kbase + (long)(q0 + w * 16 + lr) * DD + lg * 8;
#pragma unroll
    for (int c = 0; c < 4; c++) qf[c] = *(const short8*)(qp + c * 32);
  }
  f32x4 oacc[8] = {};
  float mprev[4] = {-1e30f, -1e30f, -1e30f, -1e30f};
  float lsum[4] = {0.f, 0.f, 0.f, 0.f};

  const int krow = t >> 3, kcol = (t & 7) * 16;
  const int vrow = t >> 2, vcol = (t & 3) * 16;
  for (int kb = 0; kb < LL; kb += 64) {
    {
      const u16* kp = Kb + kbase + (long)(kb + krow) * DD + kcol;
      *(u32x4*)&Ks[krow][kcol] = *(const u32x4*)(kp);
      *(u32x4*)&Ks[krow][kcol + 8] = *(const u32x4*)(kp + 8);
      const u16* vp = VT + vtbase + (long)vrow * LL + kb + vcol;
      *(u32x4*)&VTs[vrow][vcol] = *(const u32x4*)(vp);
      *(u32x4*)&VTs[vrow][vcol + 8] = *(const u32x4*)(vp + 8);
    }
    __syncthreads();

    f32x4 s[4] = {};
#pragma unroll
    for (int jc = 0; jc < 4; jc++)
#pragma unroll
      for (int c = 0; c < 4; c++) {
        short8 kf = *(const short8*)&Ks[jc * 16 + lr][c * 32 + lg * 8];
        s[jc] =
            __builtin_amdgcn_mfma_f32_16x16x32_bf16(qf[c], kf, s[jc], 0, 0, 0);
      }

    float mnew[4], alpha[4], rs[4];
#pragma unroll
    for (int r = 0; r < 4; r++) {
      float mx = fmaxf(fmaxf(s[0][r], s[1][r]), fmaxf(s[2][r], s[3][r]));
      mx = fmaxf(mx, __shfl_xor(mx, 1, 64));
      mx = fmaxf(mx, __shfl_xor(mx, 2, 64));
      mx = fmaxf(mx, __shfl_xor(mx, 4, 64));
      mx = fmaxf(mx, __shfl_xor(mx, 8, 64));
      mnew[r] = fmaxf(mprev[r], mx);
      alpha[r] = __expf(mprev[r] - mnew[r]);
      mprev[r] = mnew[r];
      rs[r] = 0.f;
    }
#pragma unroll
    for (int jc = 0; jc < 4; jc++)
#pragma unroll
      for (int r = 0; r < 4; r++) {
        float p = __expf(s[jc][r] - mnew[r]);
        rs[r] += p;
        Pw[w][lg * 4 + r][jc * 16 + lr] = f2b(p);
      }
#pragma unroll
    for (int r = 0; r < 4; r++) {
      rs[r] += __shfl_xor(rs[r], 1, 64);
      rs[r] += __shfl_xor(rs[r], 2, 64);
      rs[r] += __shfl_xor(rs[r], 4, 64);
      rs[r] += __shfl_xor(rs[r], 8, 64);
      lsum[r] = lsum[r] * alpha[r] + rs[r];
    }
#pragma unroll
    for (int d8 = 0; d8 < 8; d8++)
#pragma unroll
      for (int r = 0; r < 4; r++) oacc[d8][r] *= alpha[r];

#pragma unroll
    for (int kk = 0; kk < 2; kk++) {
      short8 pf = *(const short8*)&Pw[w][lr][kk * 32 + lg * 8];
#pragma unroll
      for (int d8 = 0; d8 < 8; d8++) {
        short8 vf = *(const short8*)&VTs[d8 * 16 + lr][kk * 32 + lg * 8];
        oacc[d8] =
            __builtin_amdgcn_mfma_f32_16x16x32_bf16(pf, vf, oacc[d8], 0, 0, 0);
      }
    }
    __syncthreads();
  }
#pragma unroll
  for (int r = 0; r < 4; r++) {
    float inv = 1.f / lsum[r];
    float* cp = ctx + kbase + (long)(q0 + w * 16 + lg * 4 + r) * DD;
#pragma unroll
    for (int d8 = 0; d8 < 8; d8++) cp[d8 * 16 + lr] = oacc[d8][r] * inv;
  }
}

// ---------------- residual + layernorm; writes fp32 and/or bf16 ----------
__global__ __launch_bounds__(256) void ln_k(const float* __restrict__ X,
                                            const float* __restrict__ R,
                                            const float* __restrict__ gamma,
                                            const float* __restrict__ beta,
                                            float* __restrict__ Hf,
                                            u16* __restrict__ Hb) {
  const int row = blockIdx.x, t = threadIdx.x;
  const long off = (long)row * DD + t * 4;
  f32x4 v = *(const f32x4*)(X + off);
  f32x4 rv = *(const f32x4*)(R + off);
#pragma unroll
  for (int i = 0; i < 4; i++) v[i] += rv[i];
  float s = v[0] + v[1] + v[2] + v[3];
  float q = v[0] * v[0] + v[1] * v[1] + v[2] * v[2] + v[3] * v[3];
#pragma unroll
  for (int m = 32; m >= 1; m >>= 1) {
    s += __shfl_xor(s, m, 64);
    q += __shfl_xor(q, m, 64);
  }
  __shared__ float red[8];
  if ((t & 63) == 0) {
    red[t >> 6] = s;
    red[4 + (t >> 6)] = q;
  }
  __syncthreads();
  s = red[0] + red[1] + red[2] + red[3];
  q = red[4] + red[5] + red[6] + red[7];
  const float mean = s * (1.f / 1024.f);
  const float var = q * (1.f / 1024.f) - mean * mean;
  const float rstd = rsqrtf(var + 1e-12f);
  f32x4 g = *(const f32x4*)(gamma + t * 4);
  f32x4 be = *(const f32x4*)(beta + t * 4);
  f32x4 o;
#pragma unroll
  for (int i = 0; i < 4; i++) o[i] = g[i] * (v[i] - mean) * rstd + be[i];
  if (Hf) *(f32x4*)(Hf + off) = o;
  if (Hb) {
    u16x4 ob;
#pragma unroll
    for (int i = 0; i < 4; i++) ob[i] = f2b(o[i]);
    *(u16x4*)(Hb + off) = ob;
  }
}

// ---------------- c2: row dot wc2 + relu -> cvec[row] ----------------
__global__ __launch_bounds__(256) void c2_k(const u16* __restrict__ C,
                                            const float* __restrict__ wc2,
                                            const float* __restrict__ bc2,
                                            float* __restrict__ cvec) {
  const int row = blockIdx.x, t = threadIdx.x;
  u16x4 cv = *(const u16x4*)(C + (long)row * DD + t * 4);
  f32x4 wv = *(const f32x4*)(wc2 + t * 4);
  float s = b2f(cv[0]) * wv[0] + b2f(cv[1]) * wv[1] + b2f(cv[2]) * wv[2] +
            b2f(cv[3]) * wv[3];
#pragma unroll
  for (int m = 32; m >= 1; m >>= 1) s += __shfl_xor(s, m, 64);
  __shared__ float red[4];
  if ((t & 63) == 0) red[t >> 6] = s;
  __syncthreads();
  if (t == 0)
    cvec[row] = fmaxf(red[0] + red[1] + red[2] + red[3] + bc2[0], 0.f);
}

// ---------------- small [4,Lr]@[Lr,N] GEMM: split-K partials + reduce -----
__global__ __launch_bounds__(256) void smm_part(const float* __restrict__ Cin,
                                                const float* __restrict__ W,
                                                float* __restrict__ P, int Lr,
                                                int N, int SL) {
  const int j = blockIdx.x * 256 + threadIdx.x;
  const int l0 = blockIdx.y * SL;
  float a0 = 0, a1 = 0, a2 = 0, a3 = 0;
  for (int ll = l0; ll < l0 + SL; ll++) {
    float wv = W[(long)ll * N + j];
    a0 += Cin[ll] * wv;
    a1 += Cin[Lr + ll] * wv;
    a2 += Cin[2 * Lr + ll] * wv;
    a3 += Cin[3 * Lr + ll] * wv;
  }
  float* Pp = P + ((long)blockIdx.y * 4) * N + j;
  Pp[0] = a0;
  Pp[N] = a1;
  Pp[2 * N] = a2;
  Pp[3 * N] = a3;
}

template <bool RELU>
__global__ __launch_bounds__(256) void smm_red(const float* __restrict__ P,
                                               const float* __restrict__ bias,
                                               float* __restrict__ Out, int N,
                                               int S) {
  const int j = blockIdx.x * 256 + threadIdx.x;
#pragma unroll
  for (int b = 0; b < 4; b++) {
    float a = 0;
    for (int s = 0; s < S; s++) a += P[((long)s * 4 + b) * N + j];
    a += bias[j];
    if (RELU) a = fmaxf(a, 0.f);
    Out[(long)b * N + j] = a;
  }
}

extern "C" void kernel_launch(void* const* d_in, const int* in_sizes, int n_in,
                              void* d_out, int out_size, void* d_ws,
                              size_t ws_size, hipStream_t stream) {
  (void)in_sizes; (void)n_in; (void)out_size; (void)ws_size;
  const float* x = (const float*)d_in[0];
  const float* wq = (const float*)d_in[1];
  const float* bq = (const float*)d_in[2];
  const float* wk = (const float*)d_in[3];
  const float* bk = (const float*)d_in[4];
  const float* wv = (const float*)d_in[5];
  const float* bv = (const float*)d_in[6];
  const float* gamma = (const float*)d_in[7];
  const float* beta = (const float*)d_in[8];
  const float* wff = (const float*)d_in[9];
  const float* bff = (const float*)d_in[10];
  const float* wc1 = (const float*)d_in[11];
  const float* bc1 = (const float*)d_in[12];
  const float* wc2 = (const float*)d_in[13];
  const float* bc2 = (const float*)d_in[14];
  const float* wl1 = (const float*)d_in[15];
  const float* bl1 = (const float*)d_in[16];
  const float* wl2 = (const float*)d_in[17];
  const float* bl2 = (const float*)d_in[18];

  char* wsp = (char*)d_ws;
  size_t off = 0;
  auto take = [&](size_t bytes) -> char* {
    char* p = wsp + off;
    off += (bytes + 255) & ~(size_t)255;
    return p;
  };
  u16* xb = (u16*)take((size_t)8192 * 1024 * 2);
  u16* wqT = (u16*)take((size_t)1024 * 1024 * 2);
  u16* wkT = (u16*)take((size_t)1024 * 1024 * 2);
  u16* wvT = (u16*)take((size_t)1024 * 1024 * 2);
  u16* wffT = (u16*)take((size_t)1024 * 1024 * 2);
  u16* wc1T = (u16*)take((size_t)1024 * 1024 * 2);
  u16* qb = (u16*)take((size_t)8192 * 1024 * 2);
  u16* kbuf = (u16*)take((size_t)8192 * 1024 * 2);
  u16* vT = (u16*)take((size_t)8192 * 1024 * 2);
  float* ctxb = (float*)take((size_t)8192 * 1024 * 4);
  float* h1f = (float*)take((size_t)8192 * 1024 * 4);
  float* cvec = (float*)take(8192 * 4);
  float* c3 = (float*)take(8192 * 4);
  float* P1 = (float*)take((size_t)16 * 4 * 2048 * 4);
  float* P2 = (float*)take((size_t)16 * 4 * 256 * 4);
  u16* h1b = qb;
  u16* h2b = kbuf;
  u16* cb = vT;
  float* ff = ctxb;

  cvt_k<<<8192, 256, 0, stream>>>(x, xb, (long)8192 * 1024);
  dim3 trg(32, 32);
  tr_k<<<trg, 256, 0, stream>>>(wq, wqT);
  tr_k<<<trg, 256, 0, stream>>>(wk, wkT);
  tr_k<<<trg, 256, 0, stream>>>(wv, wvT);
  tr_k<<<trg, 256, 0, stream>>>(wff, wffT);
  tr_k<<<trg, 256, 0, stream>>>(wc1, wc1T);

  dim3 gg(8, 64);
  gemm_k<false, 1><<<gg, 256, 0, stream>>>(
      xb, wqT, bq, 0.08838834764831845f, nullptr, qb, 8192, 1024, 1024);
  gemm_k<false, 1><<<gg, 256, 0, stream>>>(xb, wkT, bk, 1.f, nullptr, kbuf,
                                           8192, 1024, 1024);
  gemm_k<false, 2><<<gg, 256, 0, stream>>>(xb, wvT, bv, 1.f, nullptr, vT,
                                           8192, 1024, 1024);
  flash_k<<<dim3(16, 32), 512, 0, stream>>>(qb, kbuf, vT, ctxb);
  ln_k<<<8192, 256, 0, stream>>>(x, ctxb, gamma, beta, h1f, h1b);
  gemm_k<true, 0><<<gg, 256, 0, stream>>>(h1b, wffT, bff, 1.f, ff, nullptr,
                                          8192, 1024, 1024);
  ln_k<<<8192, 256, 0, stream>>>(h1f, ff, gamma, beta, nullptr, h2b);
  gemm_k<true, 1><<<gg, 256, 0, stream>>>(h2b, wc1T, bc1, 1.f, nullptr, cb,
                                          8192, 1024, 1024);
  c2_k<<<8192, 256, 0, stream>>>(cb, wc2, bc2, cvec);
  smm_part<<<dim3(8, 16), 256, 0, stream>>>(cvec, wl1, P1, 2048, 2048, 128);
  smm_red<true><<<8, 256, 0, stream>>>(P1, bl1, c3, 2048, 16);
  smm_part<<<dim3(1, 16), 256, 0, stream>>>(c3, wl2, P2, 2048, 256, 128);
  smm_red<false><<<1, 256, 0, stream>>>(P2, bl2, (float*)d_out, 256, 16);
}

// Round 3
// 458.148 us; speedup vs baseline: 1.4805x; 1.1269x over previous
//
#include <hip/hip_runtime.h>

typedef unsigned short u16;
typedef unsigned int u32;
typedef __attribute__((ext_vector_type(4))) float f32x4;
typedef __attribute__((ext_vector_type(8))) short short8;
typedef __attribute__((ext_vector_type(4))) u32 u32x4;
typedef __attribute__((ext_vector_type(4))) u16 u16x4;

#define BB 4
#define LL 2048
#define DD 1024
#define HH 8
#define DHH 128

__device__ __forceinline__ u16 f2b(float f) {
  u32 u = __builtin_bit_cast(u32, f);
  u += 0x7fffu + ((u >> 16) & 1u);
  return (u16)(u >> 16);
}
__device__ __forceinline__ float b2f(u16 h) {
  u32 u = ((u32)h) << 16;
  return __builtin_bit_cast(float, u);
}

#define GLDS16(g, l)                                                          \
  __builtin_amdgcn_global_load_lds(                                           \
      (const __attribute__((address_space(1))) void*)(g),                     \
      (__attribute__((address_space(3))) void*)(l), 16, 0, 0)

// ---------------- elementwise fp32 -> bf16 ----------------
__global__ __launch_bounds__(256) void cvt_k(const float* __restrict__ X,
                                             u16* __restrict__ Xb, long n) {
  long i = ((long)blockIdx.x * 256 + threadIdx.x) * 4;
  if (i >= n) return;
  f32x4 v = *(const f32x4*)(X + i);
  u16x4 o;
#pragma unroll
  for (int k = 0; k < 4; k++) o[k] = f2b(v[k]);
  *(u16x4*)(Xb + i) = o;
}

// ---------------- 1024x1024 fp32 -> bf16 transpose (WT[n][k] = W[k][n]) ----
__global__ __launch_bounds__(256) void tr_k(const float* __restrict__ W,
                                            u16* __restrict__ WT) {
  __shared__ float tile[32][33];
  const int bx = blockIdx.x, by = blockIdx.y;
  const int tx = threadIdx.x & 31, ty = threadIdx.x >> 5;
#pragma unroll
  for (int i = 0; i < 4; i++)
    tile[ty + i * 8][tx] =
        W[(long)(by * 32 + ty + i * 8) * 1024 + bx * 32 + tx];
  __syncthreads();
#pragma unroll
  for (int i = 0; i < 4; i++)
    WT[(long)(bx * 32 + ty + i * 8) * 1024 + by * 32 + tx] =
        f2b(tile[tx][ty + i * 8]);
}

// ---------------- 128x128x32 bf16 MFMA GEMM (m97 structure) ---------------
// C = A[M,K] @ W with W given as WT[N,K]. Staging via global_load_lds x16,
// LINEAR LDS [128][32] (global_load_lds writes wave-uniform base + lane*16;
// padding would corrupt it). epilogue: (acc + bias[col]) * scale, opt relu.
// OMODE: 0 = fp32 row-major, 1 = bf16 row-major, 2 = bf16 VT layout
//        VT[(b*1024 + col)*2048 + l]  where row = b*2048 + l
template <bool RELU, int OMODE>
__global__ __launch_bounds__(256, 2) void gemm_k(
    const u16* __restrict__ A, const u16* __restrict__ BT,
    const float* __restrict__ bias, float scale, float* __restrict__ Cf,
    u16* __restrict__ Cb, int M, int N, int K) {
  __shared__ u16 As[128 * 32];
  __shared__ u16 Bs[128 * 32];
  const int t = threadIdx.x;
  const int l = t & 63, w = t >> 6;
  const int lr = l & 15, lg = l >> 4;
  const int wr = (w >> 1) * 64, wc = (w & 1) * 64;
  const long bm = (long)blockIdx.y * 128, bn = (long)blockIdx.x * 128;
  // wave w stages rows [w*32, w*32+32) of A and B as two 1KB chunks:
  // chunk lane map: row = c*16 + l/4, col = (l%4)*8  ->  lds off = lane*16B
  const int srow = l >> 2;
  const int scol = (l & 3) * 8;
  const u16* Ag0 = A + (bm + w * 32 + srow) * (long)K + scol;
  const u16* Ag1 = A + (bm + w * 32 + 16 + srow) * (long)K + scol;
  const u16* Bg0 = BT + (bn + w * 32 + srow) * (long)K + scol;
  const u16* Bg1 = BT + (bn + w * 32 + 16 + srow) * (long)K + scol;
  u16* Al0 = As + w * 1024;
  u16* Al1 = As + w * 1024 + 512;
  u16* Bl0 = Bs + w * 1024;
  u16* Bl1 = Bs + w * 1024 + 512;
  f32x4 acc[4][4] = {};
  for (int k0 = 0; k0 < K; k0 += 32) {
    GLDS16(Ag0 + k0, Al0);
    GLDS16(Ag1 + k0, Al1);
    GLDS16(Bg0 + k0, Bl0);
    GLDS16(Bg1 + k0, Bl1);
    __syncthreads();
    short8 af[4], bf[4];
#pragma unroll
    for (int i = 0; i < 4; i++)
      af[i] = *(const short8*)&As[(wr + i * 16 + lr) * 32 + lg * 8];
#pragma unroll
    for (int i = 0; i < 4; i++)
      bf[i] = *(const short8*)&Bs[(wc + i * 16 + lr) * 32 + lg * 8];
#pragma unroll
    for (int i = 0; i < 4; i++)
#pragma unroll
      for (int j = 0; j < 4; j++)
        acc[i][j] = __builtin_amdgcn_mfma_f32_16x16x32_bf16(af[i], bf[j],
                                                            acc[i][j], 0, 0, 0);
    __syncthreads();
  }
#pragma unroll
  for (int i = 0; i < 4; i++)
#pragma unroll
    for (int j = 0; j < 4; j++) {
      long col = bn + wc + j * 16 + lr;
      float bv = bias[col];
      if (OMODE == 2) {
        long row0 = bm + wr + i * 16 + lg * 4;
        long b = row0 >> 11, l0 = row0 & 2047;
        u16x4 ov;
#pragma unroll
        for (int r = 0; r < 4; r++) {
          float v2 = (acc[i][j][r] + bv) * scale;
          if (RELU) v2 = fmaxf(v2, 0.f);
          ov[r] = f2b(v2);
        }
        *(u16x4*)(Cb + (b * 1024 + col) * 2048 + l0) = ov;
      } else {
#pragma unroll
        for (int r = 0; r < 4; r++) {
          long row = bm + wr + i * 16 + lg * 4 + r;
          float v2 = (acc[i][j][r] + bv) * scale;
          if (RELU) v2 = fmaxf(v2, 0.f);
          if (OMODE == 1)
            Cb[row * N + col] = f2b(v2);
          else
            Cf[row * N + col] = v2;
        }
      }
    }
}

// ---------------- flash attention v2: grid (L/128, B*H), 8 waves x 16 q rows
__global__ __launch_bounds__(512, 4) void flash_k(const u16* __restrict__ Q,
                                                  const u16* __restrict__ Kb,
                                                  const u16* __restrict__ VT,
                                                  float* __restrict__ ctx) {
  __shared__ u16 Ks[64][136];    // K tile [kv][d]
  __shared__ u16 VTs[128][72];   // V^T tile [d][kv]
  __shared__ u16 Pw[8][16][76];  // per-wave P relayout
  const int t = threadIdx.x;
  const int l = t & 63, w = t >> 6;
  const int lr = l & 15, lg = l >> 4;
  const int bh = blockIdx.y;
  const int b = bh >> 3, h = bh & 7;
  const long kbase = ((long)b * LL) * DD + h * DHH;
  const long vtbase = ((long)(b * 8 + h) * DHH) * LL;
  const int q0 = blockIdx.x * 128;

  short8 qf[4];
  {
    const u16* qp = Q + kbase + (long)(q0 + w * 16 + lr) * DD + lg * 8;
#pragma unroll
    for (int c = 0; c < 4; c++) qf[c] = *(const short8*)(qp + c * 32);
  }
  f32x4 oacc[8] = {};
  float mprev[4] = {-1e30f, -1e30f, -1e30f, -1e30f};
  float lsum[4] = {0.f, 0.f, 0.f, 0.f};

  const int krow = t >> 3, kcol = (t & 7) * 16;
  const int vrow = t >> 2, vcol = (t & 3) * 16;
  for (int kb = 0; kb < LL; kb += 64) {
    {
      const u16* kp = Kb + kbase + (long)(kb + krow) * DD + kcol;
      *(u32x4*)&Ks[krow][kcol] = *(const u32x4*)(kp);
      *(u32x4*)&Ks[krow][kcol + 8] = *(const u32x4*)(kp + 8);
      const u16* vp = VT + vtbase + (long)vrow * LL + kb + vcol;
      *(u32x4*)&VTs[vrow][vcol] = *(const u32x4*)(vp);
      *(u32x4*)&VTs[vrow][vcol + 8] = *(const u32x4*)(vp + 8);
    }
    __syncthreads();

    f32x4 s[4] = {};
#pragma unroll
    for (int jc = 0; jc < 4; jc++)
#pragma unroll
      for (int c = 0; c < 4; c++) {
        short8 kf = *(const short8*)&Ks[jc * 16 + lr][c * 32 + lg * 8];
        s[jc] =
            __builtin_amdgcn_mfma_f32_16x16x32_bf16(qf[c], kf, s[jc], 0, 0, 0);
      }

    float mnew[4], alpha[4], rs[4];
#pragma unroll
    for (int r = 0; r < 4; r++) {
      float mx = fmaxf(fmaxf(s[0][r], s[1][r]), fmaxf(s[2][r], s[3][r]));
      mx = fmaxf(mx, __shfl_xor(mx, 1, 64));
      mx = fmaxf(mx, __shfl_xor(mx, 2, 64));
      mx = fmaxf(mx, __shfl_xor(mx, 4, 64));
      mx = fmaxf(mx, __shfl_xor(mx, 8, 64));
      mnew[r] = fmaxf(mprev[r], mx);
      alpha[r] = __expf(mprev[r] - mnew[r]);
      mprev[r] = mnew[r];
      rs[r] = 0.f;
    }
#pragma unroll
    for (int jc = 0; jc < 4; jc++)
#pragma unroll
      for (int r = 0; r < 4; r++) {
        float p = __expf(s[jc][r] - mnew[r]);
        rs[r] += p;
        Pw[w][lg * 4 + r][jc * 16 + lr] = f2b(p);
      }
#pragma unroll
    for (int r = 0; r < 4; r++) {
      rs[r] += __shfl_xor(rs[r], 1, 64);
      rs[r] += __shfl_xor(rs[r], 2, 64);
      rs[r] += __shfl_xor(rs[r], 4, 64);
      rs[r] += __shfl_xor(rs[r], 8, 64);
      lsum[r] = lsum[r] * alpha[r] + rs[r];
    }
#pragma unroll
    for (int d8 = 0; d8 < 8; d8++)
#pragma unroll
      for (int r = 0; r < 4; r++) oacc[d8][r] *= alpha[r];

#pragma unroll
    for (int kk = 0; kk < 2; kk++) {
      short8 pf = *(const short8*)&Pw[w][lr][kk * 32 + lg * 8];
#pragma unroll
      for (int d8 = 0; d8 < 8; d8++) {
        short8 vf = *(const short8*)&VTs[d8 * 16 + lr][kk * 32 + lg * 8];
        oacc[d8] =
            __builtin_amdgcn_mfma_f32_16x16x32_bf16(pf, vf, oacc[d8], 0, 0, 0);
      }
    }
    __syncthreads();
  }
#pragma unroll
  for (int r = 0; r < 4; r++) {
    float inv = 1.f / lsum[r];
    float* cp = ctx + kbase + (long)(q0 + w * 16 + lg * 4 + r) * DD;
#pragma unroll
    for (int d8 = 0; d8 < 8; d8++) cp[d8 * 16 + lr] = oacc[d8][r] * inv;
  }
}

// ---------------- residual + layernorm; writes fp32 and/or bf16 ----------
__global__ __launch_bounds__(256) void ln_k(const float* __restrict__ X,
                                            const float* __restrict__ R,
                                            const float* __restrict__ gamma,
                                            const float* __restrict__ beta,
                                            float* __restrict__ Hf,
                                            u16* __restrict__ Hb) {
  const int row = blockIdx.x, t = threadIdx.x;
  const long off = (long)row * DD + t * 4;
  f32x4 v = *(const f32x4*)(X + off);
  f32x4 rv = *(const f32x4*)(R + off);
#pragma unroll
  for (int i = 0; i < 4; i++) v[i] += rv[i];
  float s = v[0] + v[1] + v[2] + v[3];
  float q = v[0] * v[0] + v[1] * v[1] + v[2] * v[2] + v[3] * v[3];
#pragma unroll
  for (int m = 32; m >= 1; m >>= 1) {
    s += __shfl_xor(s, m, 64);
    q += __shfl_xor(q, m, 64);
  }
  __shared__ float red[8];
  if ((t & 63) == 0) {
    red[t >> 6] = s;
    red[4 + (t >> 6)] = q;
  }
  __syncthreads();
  s = red[0] + red[1] + red[2] + red[3];
  q = red[4] + red[5] + red[6] + red[7];
  const float mean = s * (1.f / 1024.f);
  const float var = q * (1.f / 1024.f) - mean * mean;
  const float rstd = rsqrtf(var + 1e-12f);
  f32x4 g = *(const f32x4*)(gamma + t * 4);
  f32x4 be = *(const f32x4*)(beta + t * 4);
  f32x4 o;
#pragma unroll
  for (int i = 0; i < 4; i++) o[i] = g[i] * (v[i] - mean) * rstd + be[i];
  if (Hf) *(f32x4*)(Hf + off) = o;
  if (Hb) {
    u16x4 ob;
#pragma unroll
    for (int i = 0; i < 4; i++) ob[i] = f2b(o[i]);
    *(u16x4*)(Hb + off) = ob;
  }
}

// ---------------- c2: row dot wc2 + relu -> cvec[row] ----------------
__global__ __launch_bounds__(256) void c2_k(const u16* __restrict__ C,
                                            const float* __restrict__ wc2,
                                            const float* __restrict__ bc2,
                                            float* __restrict__ cvec) {
  const int row = blockIdx.x, t = threadIdx.x;
  u16x4 cv = *(const u16x4*)(C + (long)row * DD + t * 4);
  f32x4 wv = *(const f32x4*)(wc2 + t * 4);
  float s = b2f(cv[0]) * wv[0] + b2f(cv[1]) * wv[1] + b2f(cv[2]) * wv[2] +
            b2f(cv[3]) * wv[3];
#pragma unroll
  for (int m = 32; m >= 1; m >>= 1) s += __shfl_xor(s, m, 64);
  __shared__ float red[4];
  if ((t & 63) == 0) red[t >> 6] = s;
  __syncthreads();
  if (t == 0)
    cvec[row] = fmaxf(red[0] + red[1] + red[2] + red[3] + bc2[0], 0.f);
}

// ---------------- small [4,Lr]@[Lr,N] GEMM: split-K partials + reduce -----
__global__ __launch_bounds__(256) void smm_part(const float* __restrict__ Cin,
                                                const float* __restrict__ W,
                                                float* __restrict__ P, int Lr,
                                                int N, int SL) {
  const int j = blockIdx.x * 256 + threadIdx.x;
  const int l0 = blockIdx.y * SL;
  float a0 = 0, a1 = 0, a2 = 0, a3 = 0;
  for (int ll = l0; ll < l0 + SL; ll++) {
    float wv = W[(long)ll * N + j];
    a0 += Cin[ll] * wv;
    a1 += Cin[Lr + ll] * wv;
    a2 += Cin[2 * Lr + ll] * wv;
    a3 += Cin[3 * Lr + ll] * wv;
  }
  float* Pp = P + ((long)blockIdx.y * 4) * N + j;
  Pp[0] = a0;
  Pp[N] = a1;
  Pp[2 * N] = a2;
  Pp[3 * N] = a3;
}

template <bool RELU>
__global__ __launch_bounds__(256) void smm_red(const float* __restrict__ P,
                                               const float* __restrict__ bias,
                                               float* __restrict__ Out, int N,
                                               int S) {
  const int j = blockIdx.x * 256 + threadIdx.x;
#pragma unroll
  for (int b = 0; b < 4; b++) {
    float a = 0;
    for (int s = 0; s < S; s++) a += P[((long)s * 4 + b) * N + j];
    a += bias[j];
    if (RELU) a = fmaxf(a, 0.f);
    Out[(long)b * N + j] = a;
  }
}

extern "C" void kernel_launch(void* const* d_in, const int* in_sizes, int n_in,
                              void* d_out, int out_size, void* d_ws,
                              size_t ws_size, hipStream_t stream) {
  (void)in_sizes; (void)n_in; (void)out_size; (void)ws_size;
  const float* x = (const float*)d_in[0];
  const float* wq = (const float*)d_in[1];
  const float* bq = (const float*)d_in[2];
  const float* wk = (const float*)d_in[3];
  const float* bk = (const float*)d_in[4];
  const float* wv = (const float*)d_in[5];
  const float* bv = (const float*)d_in[6];
  const float* gamma = (const float*)d_in[7];
  const float* beta = (const float*)d_in[8];
  const float* wff = (const float*)d_in[9];
  const float* bff = (const float*)d_in[10];
  const float* wc1 = (const float*)d_in[11];
  const float* bc1 = (const float*)d_in[12];
  const float* wc2 = (const float*)d_in[13];
  const float* bc2 = (const float*)d_in[14];
  const float* wl1 = (const float*)d_in[15];
  const float* bl1 = (const float*)d_in[16];
  const float* wl2 = (const float*)d_in[17];
  const float* bl2 = (const float*)d_in[18];

  char* wsp = (char*)d_ws;
  size_t off = 0;
  auto take = [&](size_t bytes) -> char* {
    char* p = wsp + off;
    off += (bytes + 255) & ~(size_t)255;
    return p;
  };
  u16* xb = (u16*)take((size_t)8192 * 1024 * 2);
  u16* wqT = (u16*)take((size_t)1024 * 1024 * 2);
  u16* wkT = (u16*)take((size_t)1024 * 1024 * 2);
  u16* wvT = (u16*)take((size_t)1024 * 1024 * 2);
  u16* wffT = (u16*)take((size_t)1024 * 1024 * 2);
  u16* wc1T = (u16*)take((size_t)1024 * 1024 * 2);
  u16* qb = (u16*)take((size_t)8192 * 1024 * 2);
  u16* kbuf = (u16*)take((size_t)8192 * 1024 * 2);
  u16* vT = (u16*)take((size_t)8192 * 1024 * 2);
  float* ctxb = (float*)take((size_t)8192 * 1024 * 4);
  float* h1f = (float*)take((size_t)8192 * 1024 * 4);
  float* cvec = (float*)take(8192 * 4);
  float* c3 = (float*)take(8192 * 4);
  float* P1 = (float*)take((size_t)16 * 4 * 2048 * 4);
  float* P2 = (float*)take((size_t)16 * 4 * 256 * 4);
  u16* h1b = qb;
  u16* h2b = kbuf;
  u16* cb = vT;
  float* ff = ctxb;

  cvt_k<<<8192, 256, 0, stream>>>(x, xb, (long)8192 * 1024);
  dim3 trg(32, 32);
  tr_k<<<trg, 256, 0, stream>>>(wq, wqT);
  tr_k<<<trg, 256, 0, stream>>>(wk, wkT);
  tr_k<<<trg, 256, 0, stream>>>(wv, wvT);
  tr_k<<<trg, 256, 0, stream>>>(wff, wffT);
  tr_k<<<trg, 256, 0, stream>>>(wc1, wc1T);

  dim3 gg(8, 64);
  gemm_k<false, 1><<<gg, 256, 0, stream>>>(
      xb, wqT, bq, 0.08838834764831845f, nullptr, qb, 8192, 1024, 1024);
  gemm_k<false, 1><<<gg, 256, 0, stream>>>(xb, wkT, bk, 1.f, nullptr, kbuf,
                                           8192, 1024, 1024);
  gemm_k<false, 2><<<gg, 256, 0, stream>>>(xb, wvT, bv, 1.f, nullptr, vT,
                                           8192, 1024, 1024);
  flash_k<<<dim3(16, 32), 512, 0, stream>>>(qb, kbuf, vT, ctxb);
  ln_k<<<8192, 256, 0, stream>>>(x, ctxb, gamma, beta, h1f, h1b);
  gemm_k<true, 0><<<gg, 256, 0, stream>>>(h1b, wffT, bff, 1.f, ff, nullptr,
                                          8192, 1024, 1024);
  ln_k<<<8192, 256, 0, stream>>>(h1f, ff, gamma, beta, nullptr, h2b);
  gemm_k<true, 1><<<gg, 256, 0, stream>>>(h2b, wc1T, bc1, 1.f, nullptr, cb,
                                          8192, 1024, 1024);
  c2_k<<<8192, 256, 0, stream>>>(cb, wc2, bc2, cvec);
  smm_part<<<dim3(8, 16), 256, 0, stream>>>(cvec, wl1, P1, 2048, 2048, 128);
  smm_red<true><<<8, 256, 0, stream>>>(P1, bl1, c3, 2048, 16);
  smm_part<<<dim3(1, 16), 256, 0, stream>>>(c3, wl2, P2, 2048, 256, 128);
  smm_red<false><<<1, 256, 0, stream>>>(P2, bl2, (float*)d_out, 256, 16);
}

// Round 4
// 429.733 us; speedup vs baseline: 1.5784x; 1.0661x over previous
//
#include <hip/hip_runtime.h>

typedef unsigned short u16;
typedef unsigned int u32;
typedef __attribute__((ext_vector_type(4))) float f32x4;
typedef __attribute__((ext_vector_type(8))) short short8;
typedef __attribute__((ext_vector_type(4))) u32 u32x4;
typedef __attribute__((ext_vector_type(4))) u16 u16x4;

#define BB 4
#define LL 2048
#define DD 1024
#define HH 8
#define DHH 128

__device__ __forceinline__ u16 f2b(float f) {
  u32 u = __builtin_bit_cast(u32, f);
  u += 0x7fffu + ((u >> 16) & 1u);
  return (u16)(u >> 16);
}
__device__ __forceinline__ float b2f(u16 h) {
  u32 u = ((u32)h) << 16;
  return __builtin_bit_cast(float, u);
}
// raw v_exp_f32: D = 2^S0 (ISA §3) — exp2 with no mul
__device__ __forceinline__ float exp2_fast(float x) {
  float r;
  asm("v_exp_f32 %0, %1" : "=v"(r) : "v"(x));
  return r;
}

#define GLDS16(g, l)                                                          \
  __builtin_amdgcn_global_load_lds(                                           \
      (const __attribute__((address_space(1))) void*)(g),                     \
      (__attribute__((address_space(3))) void*)(l), 16, 0, 0)

// ---------------- elementwise fp32 -> bf16 ----------------
__global__ __launch_bounds__(256) void cvt_k(const float* __restrict__ X,
                                             u16* __restrict__ Xb, long n) {
  long i = ((long)blockIdx.x * 256 + threadIdx.x) * 4;
  if (i >= n) return;
  f32x4 v = *(const f32x4*)(X + i);
  u16x4 o;
#pragma unroll
  for (int k = 0; k < 4; k++) o[k] = f2b(v[k]);
  *(u16x4*)(Xb + i) = o;
}

// ---------------- 1024x1024 fp32 -> bf16 transpose (WT[n][k] = W[k][n]) ----
__global__ __launch_bounds__(256) void tr_k(const float* __restrict__ W,
                                            u16* __restrict__ WT) {
  __shared__ float tile[32][33];
  const int bx = blockIdx.x, by = blockIdx.y;
  const int tx = threadIdx.x & 31, ty = threadIdx.x >> 5;
#pragma unroll
  for (int i = 0; i < 4; i++)
    tile[ty + i * 8][tx] =
        W[(long)(by * 32 + ty + i * 8) * 1024 + bx * 32 + tx];
  __syncthreads();
#pragma unroll
  for (int i = 0; i < 4; i++)
    WT[(long)(bx * 32 + ty + i * 8) * 1024 + by * 32 + tx] =
        f2b(tile[tx][ty + i * 8]);
}

// ---------------- 128x128x32 bf16 MFMA GEMM (m97 structure + T1 swizzle) ---
// C = A[M,K] @ W with W given as WT[N,K]. Staging via global_load_lds x16,
// LINEAR LDS [128][32]. epilogue: (acc + bias[col]) * scale, opt relu.
// OMODE: 0 = fp32 row-major, 1 = bf16 row-major, 2 = bf16 VT layout
template <bool RELU, int OMODE>
__global__ __launch_bounds__(256, 2) void gemm_k(
    const u16* __restrict__ A, const u16* __restrict__ BT,
    const float* __restrict__ bias, float scale, float* __restrict__ Cf,
    u16* __restrict__ Cb, int M, int N, int K) {
  __shared__ u16 As[128 * 32];
  __shared__ u16 Bs[128 * 32];
  // T1: XCD-aware swizzle; grid size is a multiple of 8 (512) -> bijective.
  const int nwg = gridDim.x * gridDim.y;
  const int bid = blockIdx.x + blockIdx.y * gridDim.x;
  const int swz = (bid & 7) * (nwg >> 3) + (bid >> 3);
  const int bxi = swz % gridDim.x, byi = swz / gridDim.x;
  const int t = threadIdx.x;
  const int l = t & 63, w = t >> 6;
  const int lr = l & 15, lg = l >> 4;
  const int wr = (w >> 1) * 64, wc = (w & 1) * 64;
  const long bm = (long)byi * 128, bn = (long)bxi * 128;
  const int srow = l >> 2;
  const int scol = (l & 3) * 8;
  const u16* Ag0 = A + (bm + w * 32 + srow) * (long)K + scol;
  const u16* Ag1 = A + (bm + w * 32 + 16 + srow) * (long)K + scol;
  const u16* Bg0 = BT + (bn + w * 32 + srow) * (long)K + scol;
  const u16* Bg1 = BT + (bn + w * 32 + 16 + srow) * (long)K + scol;
  u16* Al0 = As + w * 1024;
  u16* Al1 = As + w * 1024 + 512;
  u16* Bl0 = Bs + w * 1024;
  u16* Bl1 = Bs + w * 1024 + 512;
  f32x4 acc[4][4] = {};
  for (int k0 = 0; k0 < K; k0 += 32) {
    GLDS16(Ag0 + k0, Al0);
    GLDS16(Ag1 + k0, Al1);
    GLDS16(Bg0 + k0, Bl0);
    GLDS16(Bg1 + k0, Bl1);
    __syncthreads();
    short8 af[4], bf[4];
#pragma unroll
    for (int i = 0; i < 4; i++)
      af[i] = *(const short8*)&As[(wr + i * 16 + lr) * 32 + lg * 8];
#pragma unroll
    for (int i = 0; i < 4; i++)
      bf[i] = *(const short8*)&Bs[(wc + i * 16 + lr) * 32 + lg * 8];
#pragma unroll
    for (int i = 0; i < 4; i++)
#pragma unroll
      for (int j = 0; j < 4; j++)
        acc[i][j] = __builtin_amdgcn_mfma_f32_16x16x32_bf16(af[i], bf[j],
                                                            acc[i][j], 0, 0, 0);
    __syncthreads();
  }
#pragma unroll
  for (int i = 0; i < 4; i++)
#pragma unroll
    for (int j = 0; j < 4; j++) {
      long col = bn + wc + j * 16 + lr;
      float bv = bias[col];
      if (OMODE == 2) {
        long row0 = bm + wr + i * 16 + lg * 4;
        long b = row0 >> 11, l0 = row0 & 2047;
        u16x4 ov;
#pragma unroll
        for (int r = 0; r < 4; r++) {
          float v2 = (acc[i][j][r] + bv) * scale;
          if (RELU) v2 = fmaxf(v2, 0.f);
          ov[r] = f2b(v2);
        }
        *(u16x4*)(Cb + (b * 1024 + col) * 2048 + l0) = ov;
      } else {
#pragma unroll
        for (int r = 0; r < 4; r++) {
          long row = bm + wr + i * 16 + lg * 4 + r;
          float v2 = (acc[i][j][r] + bv) * scale;
          if (RELU) v2 = fmaxf(v2, 0.f);
          if (OMODE == 1)
            Cb[row * N + col] = f2b(v2);
          else
            Cf[row * N + col] = v2;
        }
      }
    }
}

// ---------------- flash attention v3: 8 waves x 16 q rows, T14 + T13 + T1 --
// Softmax in base-2: Q is pre-scaled by log2(e)/sqrt(DH) in the Q-GEMM.
__global__ __launch_bounds__(512, 4) void flash_k(const u16* __restrict__ Q,
                                                  const u16* __restrict__ Kb,
                                                  const u16* __restrict__ VT,
                                                  float* __restrict__ ctx) {
  __shared__ u16 Ks[64][136];    // K tile [kv][d]
  __shared__ u16 VTs[128][72];   // V^T tile [d][kv]
  __shared__ u16 Pw[8][16][76];  // per-wave P relayout
  const int nwg = gridDim.x * gridDim.y;
  const int bid = blockIdx.x + blockIdx.y * gridDim.x;
  const int swz = (bid & 7) * (nwg >> 3) + (bid >> 3);
  const int bxi = swz % gridDim.x, byi = swz / gridDim.x;
  const int t = threadIdx.x;
  const int l = t & 63, w = t >> 6;
  const int lr = l & 15, lg = l >> 4;
  const int b = byi >> 3, h = byi & 7;
  const long kbase = ((long)b * LL) * DD + h * DHH;
  const long vtbase = ((long)(b * 8 + h) * DHH) * LL;
  const int q0 = bxi * 128;

  short8 qf[4];
  {
    const u16* qp = Q + kbase + (long)(q0 + w * 16 + lr) * DD + lg * 8;
#pragma unroll
    for (int c = 0; c < 4; c++) qf[c] = *(const short8*)(qp + c * 32);
  }
  f32x4 oacc[8] = {};
  float mprev[4] = {-1e30f, -1e30f, -1e30f, -1e30f};
  float lsum[4] = {0.f, 0.f, 0.f, 0.f};

  const int krow = t >> 3, kcol = (t & 7) * 16;
  const int vrow = t >> 2, vcol = (t & 3) * 16;
  // T14: register-staged prefetch (issue early / LDS-write late)
  u32x4 kr0, kr1, vr0, vr1;
  {
    const u16* kp = Kb + kbase + (long)krow * DD + kcol;
    kr0 = *(const u32x4*)(kp);
    kr1 = *(const u32x4*)(kp + 8);
    const u16* vp = VT + vtbase + (long)vrow * LL + vcol;
    vr0 = *(const u32x4*)(vp);
    vr1 = *(const u32x4*)(vp + 8);
  }
  for (int kb = 0; kb < LL; kb += 64) {
    *(u32x4*)&Ks[krow][kcol] = kr0;
    *(u32x4*)&Ks[krow][kcol + 8] = kr1;
    *(u32x4*)&VTs[vrow][vcol] = vr0;
    *(u32x4*)&VTs[vrow][vcol + 8] = vr1;
    __syncthreads();
    if (kb + 64 < LL) {  // issue next tile's loads; land after next barrier
      const u16* kp = Kb + kbase + (long)(kb + 64 + krow) * DD + kcol;
      kr0 = *(const u32x4*)(kp);
      kr1 = *(const u32x4*)(kp + 8);
      const u16* vp = VT + vtbase + (long)vrow * LL + kb + 64 + vcol;
      vr0 = *(const u32x4*)(vp);
      vr1 = *(const u32x4*)(vp + 8);
    }

    f32x4 s[4] = {};
#pragma unroll
    for (int jc = 0; jc < 4; jc++)
#pragma unroll
      for (int c = 0; c < 4; c++) {
        short8 kf = *(const short8*)&Ks[jc * 16 + lr][c * 32 + lg * 8];
        s[jc] =
            __builtin_amdgcn_mfma_f32_16x16x32_bf16(qf[c], kf, s[jc], 0, 0, 0);
      }

    // tile max per row (base-2 domain)
    float mnew[4];
    bool need = false;
#pragma unroll
    for (int r = 0; r < 4; r++) {
      float mx = fmaxf(fmaxf(s[0][r], s[1][r]), fmaxf(s[2][r], s[3][r]));
      mx = fmaxf(mx, __shfl_xor(mx, 1, 64));
      mx = fmaxf(mx, __shfl_xor(mx, 2, 64));
      mx = fmaxf(mx, __shfl_xor(mx, 4, 64));
      mx = fmaxf(mx, __shfl_xor(mx, 8, 64));
      mnew[r] = mx;
      need = need || (mx > mprev[r] + 8.f);
    }
    // T13 defer-max: rescale only when some row's max grew past threshold
    if (__any((int)need)) {
#pragma unroll
      for (int r = 0; r < 4; r++) {
        float mn = fmaxf(mprev[r], mnew[r]);
        float alpha = exp2_fast(mprev[r] - mn);
        mprev[r] = mn;
        lsum[r] *= alpha;
#pragma unroll
        for (int d8 = 0; d8 < 8; d8++) oacc[d8][r] *= alpha;
      }
    }
    float rs[4] = {0.f, 0.f, 0.f, 0.f};
#pragma unroll
    for (int jc = 0; jc < 4; jc++)
#pragma unroll
      for (int r = 0; r < 4; r++) {
        float p = exp2_fast(s[jc][r] - mprev[r]);
        rs[r] += p;
        Pw[w][lg * 4 + r][jc * 16 + lr] = f2b(p);
      }
#pragma unroll
    for (int r = 0; r < 4; r++) {
      rs[r] += __shfl_xor(rs[r], 1, 64);
      rs[r] += __shfl_xor(rs[r], 2, 64);
      rs[r] += __shfl_xor(rs[r], 4, 64);
      rs[r] += __shfl_xor(rs[r], 8, 64);
      lsum[r] += rs[r];
    }

#pragma unroll
    for (int kk = 0; kk < 2; kk++) {
      short8 pf = *(const short8*)&Pw[w][lr][kk * 32 + lg * 8];
#pragma unroll
      for (int d8 = 0; d8 < 8; d8++) {
        short8 vf = *(const short8*)&VTs[d8 * 16 + lr][kk * 32 + lg * 8];
        oacc[d8] =
            __builtin_amdgcn_mfma_f32_16x16x32_bf16(pf, vf, oacc[d8], 0, 0, 0);
      }
    }
    __syncthreads();
  }
#pragma unroll
  for (int r = 0; r < 4; r++) {
    float inv = 1.f / lsum[r];
    float* cp = ctx + kbase + (long)(q0 + w * 16 + lg * 4 + r) * DD;
#pragma unroll
    for (int d8 = 0; d8 < 8; d8++) cp[d8 * 16 + lr] = oacc[d8][r] * inv;
  }
}

// ---------------- residual + layernorm; writes fp32 and/or bf16 ----------
__global__ __launch_bounds__(256) void ln_k(const float* __restrict__ X,
                                            const float* __restrict__ R,
                                            const float* __restrict__ gamma,
                                            const float* __restrict__ beta,
                                            float* __restrict__ Hf,
                                            u16* __restrict__ Hb) {
  const int row = blockIdx.x, t = threadIdx.x;
  const long off = (long)row * DD + t * 4;
  f32x4 v = *(const f32x4*)(X + off);
  f32x4 rv = *(const f32x4*)(R + off);
#pragma unroll
  for (int i = 0; i < 4; i++) v[i] += rv[i];
  float s = v[0] + v[1] + v[2] + v[3];
  float q = v[0] * v[0] + v[1] * v[1] + v[2] * v[2] + v[3] * v[3];
#pragma unroll
  for (int m = 32; m >= 1; m >>= 1) {
    s += __shfl_xor(s, m, 64);
    q += __shfl_xor(q, m, 64);
  }
  __shared__ float red[8];
  if ((t & 63) == 0) {
    red[t >> 6] = s;
    red[4 + (t >> 6)] = q;
  }
  __syncthreads();
  s = red[0] + red[1] + red[2] + red[3];
  q = red[4] + red[5] + red[6] + red[7];
  const float mean = s * (1.f / 1024.f);
  const float var = q * (1.f / 1024.f) - mean * mean;
  const float rstd = rsqrtf(var + 1e-12f);
  f32x4 g = *(const f32x4*)(gamma + t * 4);
  f32x4 be = *(const f32x4*)(beta + t * 4);
  f32x4 o;
#pragma unroll
  for (int i = 0; i < 4; i++) o[i] = g[i] * (v[i] - mean) * rstd + be[i];
  if (Hf) *(f32x4*)(Hf + off) = o;
  if (Hb) {
    u16x4 ob;
#pragma unroll
    for (int i = 0; i < 4; i++) ob[i] = f2b(o[i]);
    *(u16x4*)(Hb + off) = ob;
  }
}

// ---------------- c2: row dot wc2 + relu -> cvec[row] ----------------
__global__ __launch_bounds__(256) void c2_k(const u16* __restrict__ C,
                                            const float* __restrict__ wc2,
                                            const float* __restrict__ bc2,
                                            float* __restrict__ cvec) {
  const int row = blockIdx.x, t = threadIdx.x;
  u16x4 cv = *(const u16x4*)(C + (long)row * DD + t * 4);
  f32x4 wv = *(const f32x4*)(wc2 + t * 4);
  float s = b2f(cv[0]) * wv[0] + b2f(cv[1]) * wv[1] + b2f(cv[2]) * wv[2] +
            b2f(cv[3]) * wv[3];
#pragma unroll
  for (int m = 32; m >= 1; m >>= 1) s += __shfl_xor(s, m, 64);
  __shared__ float red[4];
  if ((t & 63) == 0) red[t >> 6] = s;
  __syncthreads();
  if (t == 0)
    cvec[row] = fmaxf(red[0] + red[1] + red[2] + red[3] + bc2[0], 0.f);
}

// ---------------- small [4,Lr]@[Lr,N] GEMM: split-K partials + reduce -----
__global__ __launch_bounds__(256) void smm_part(const float* __restrict__ Cin,
                                                const float* __restrict__ W,
                                                float* __restrict__ P, int Lr,
                                                int N, int SL) {
  const int j = blockIdx.x * 256 + threadIdx.x;
  const int l0 = blockIdx.y * SL;
  float a0 = 0, a1 = 0, a2 = 0, a3 = 0;
  for (int ll = l0; ll < l0 + SL; ll++) {
    float wv = W[(long)ll * N + j];
    a0 += Cin[ll] * wv;
    a1 += Cin[Lr + ll] * wv;
    a2 += Cin[2 * Lr + ll] * wv;
    a3 += Cin[3 * Lr + ll] * wv;
  }
  float* Pp = P + ((long)blockIdx.y * 4) * N + j;
  Pp[0] = a0;
  Pp[N] = a1;
  Pp[2 * N] = a2;
  Pp[3 * N] = a3;
}

template <bool RELU>
__global__ __launch_bounds__(256) void smm_red(const float* __restrict__ P,
                                               const float* __restrict__ bias,
                                               float* __restrict__ Out, int N,
                                               int S) {
  const int j = blockIdx.x * 256 + threadIdx.x;
#pragma unroll
  for (int b = 0; b < 4; b++) {
    float a = 0;
    for (int s = 0; s < S; s++) a += P[((long)s * 4 + b) * N + j];
    a += bias[j];
    if (RELU) a = fmaxf(a, 0.f);
    Out[(long)b * N + j] = a;
  }
}

extern "C" void kernel_launch(void* const* d_in, const int* in_sizes, int n_in,
                              void* d_out, int out_size, void* d_ws,
                              size_t ws_size, hipStream_t stream) {
  (void)in_sizes; (void)n_in; (void)out_size; (void)ws_size;
  const float* x = (const float*)d_in[0];
  const float* wq = (const float*)d_in[1];
  const float* bq = (const float*)d_in[2];
  const float* wk = (const float*)d_in[3];
  const float* bk = (const float*)d_in[4];
  const float* wv = (const float*)d_in[5];
  const float* bv = (const float*)d_in[6];
  const float* gamma = (const float*)d_in[7];
  const float* beta = (const float*)d_in[8];
  const float* wff = (const float*)d_in[9];
  const float* bff = (const float*)d_in[10];
  const float* wc1 = (const float*)d_in[11];
  const float* bc1 = (const float*)d_in[12];
  const float* wc2 = (const float*)d_in[13];
  const float* bc2 = (const float*)d_in[14];
  const float* wl1 = (const float*)d_in[15];
  const float* bl1 = (const float*)d_in[16];
  const float* wl2 = (const float*)d_in[17];
  const float* bl2 = (const float*)d_in[18];

  char* wsp = (char*)d_ws;
  size_t off = 0;
  auto take = [&](size_t bytes) -> char* {
    char* p = wsp + off;
    off += (bytes + 255) & ~(size_t)255;
    return p;
  };
  u16* xb = (u16*)take((size_t)8192 * 1024 * 2);
  u16* wqT = (u16*)take((size_t)1024 * 1024 * 2);
  u16* wkT = (u16*)take((size_t)1024 * 1024 * 2);
  u16* wvT = (u16*)take((size_t)1024 * 1024 * 2);
  u16* wffT = (u16*)take((size_t)1024 * 1024 * 2);
  u16* wc1T = (u16*)take((size_t)1024 * 1024 * 2);
  u16* qb = (u16*)take((size_t)8192 * 1024 * 2);
  u16* kbuf = (u16*)take((size_t)8192 * 1024 * 2);
  u16* vT = (u16*)take((size_t)8192 * 1024 * 2);
  float* ctxb = (float*)take((size_t)8192 * 1024 * 4);
  float* h1f = (float*)take((size_t)8192 * 1024 * 4);
  float* cvec = (float*)take(8192 * 4);
  float* c3 = (float*)take(8192 * 4);
  float* P1 = (float*)take((size_t)16 * 4 * 2048 * 4);
  float* P2 = (float*)take((size_t)16 * 4 * 256 * 4);
  u16* h1b = qb;
  u16* h2b = kbuf;
  u16* cb = vT;
  float* ff = ctxb;

  cvt_k<<<8192, 256, 0, stream>>>(x, xb, (long)8192 * 1024);
  dim3 trg(32, 32);
  tr_k<<<trg, 256, 0, stream>>>(wq, wqT);
  tr_k<<<trg, 256, 0, stream>>>(wk, wkT);
  tr_k<<<trg, 256, 0, stream>>>(wv, wvT);
  tr_k<<<trg, 256, 0, stream>>>(wff, wffT);
  tr_k<<<trg, 256, 0, stream>>>(wc1, wc1T);

  dim3 gg(8, 64);
  // Q scale folds 1/sqrt(128) * log2(e) for base-2 softmax
  gemm_k<false, 1><<<gg, 256, 0, stream>>>(
      xb, wqT, bq, 0.12751743f, nullptr, qb, 8192, 1024, 1024);
  gemm_k<false, 1><<<gg, 256, 0, stream>>>(xb, wkT, bk, 1.f, nullptr, kbuf,
                                           8192, 1024, 1024);
  gemm_k<false, 2><<<gg, 256, 0, stream>>>(xb, wvT, bv, 1.f, nullptr, vT,
                                           8192, 1024, 1024);
  flash_k<<<dim3(16, 32), 512, 0, stream>>>(qb, kbuf, vT, ctxb);
  ln_k<<<8192, 256, 0, stream>>>(x, ctxb, gamma, beta, h1f, h1b);
  gemm_k<true, 0><<<gg, 256, 0, stream>>>(h1b, wffT, bff, 1.f, ff, nullptr,
                                          8192, 1024, 1024);
  ln_k<<<8192, 256, 0, stream>>>(h1f, ff, gamma, beta, nullptr, h2b);
  gemm_k<true, 1><<<gg, 256, 0, stream>>>(h2b, wc1T, bc1, 1.f, nullptr, cb,
                                          8192, 1024, 1024);
  c2_k<<<8192, 256, 0, stream>>>(cb, wc2, bc2, cvec);
  smm_part<<<dim3(8, 16), 256, 0, stream>>>(cvec, wl1, P1, 2048, 2048, 128);
  smm_red<true><<<8, 256, 0, stream>>>(P1, bl1, c3, 2048, 16);
  smm_part<<<dim3(1, 16), 256, 0, stream>>>(c3, wl2, P2, 2048, 256, 128);
  smm_red<false><<<1, 256, 0, stream>>>(P2, bl2, (float*)d_out, 256, 16);
}

// Round 5
// 399.562 us; speedup vs baseline: 1.6976x; 1.0755x over previous
//
#include <hip/hip_runtime.h>

typedef unsigned short u16;
typedef unsigned int u32;
typedef __attribute__((ext_vector_type(4))) float f32x4;
typedef __attribute__((ext_vector_type(8))) short short8;
typedef __attribute__((ext_vector_type(4))) u32 u32x4;
typedef __attribute__((ext_vector_type(4))) u16 u16x4;

#define BB 4
#define LL 2048
#define DD 1024
#define HH 8
#define DHH 128

__device__ __forceinline__ u16 f2b(float f) {
  u32 u = __builtin_bit_cast(u32, f);
  u += 0x7fffu + ((u >> 16) & 1u);
  return (u16)(u >> 16);
}
__device__ __forceinline__ float b2f(u16 h) {
  u32 u = ((u32)h) << 16;
  return __builtin_bit_cast(float, u);
}
// raw v_exp_f32: D = 2^S0 (ISA §3) — exp2 with no mul
__device__ __forceinline__ float exp2_fast(float x) {
  float r;
  asm("v_exp_f32 %0, %1" : "=v"(r) : "v"(x));
  return r;
}
__device__ __forceinline__ u32 packbf(float a, float b) {
  return (u32)f2b(a) | ((u32)f2b(b) << 16);
}
__device__ __forceinline__ u32 bperm(int srcLane, u32 v) {
  return (u32)__builtin_amdgcn_ds_bpermute(srcLane << 2, (int)v);
}

#define GLDS16(g, l)                                                          \
  __builtin_amdgcn_global_load_lds(                                           \
      (const __attribute__((address_space(1))) void*)(g),                     \
      (__attribute__((address_space(3))) void*)(l), 16, 0, 0)

// ---------------- elementwise fp32 -> bf16 ----------------
__global__ __launch_bounds__(256) void cvt_k(const float* __restrict__ X,
                                             u16* __restrict__ Xb, long n) {
  long i = ((long)blockIdx.x * 256 + threadIdx.x) * 4;
  if (i >= n) return;
  f32x4 v = *(const f32x4*)(X + i);
  u16x4 o;
#pragma unroll
  for (int k = 0; k < 4; k++) o[k] = f2b(v[k]);
  *(u16x4*)(Xb + i) = o;
}

// ---------------- 1024x1024 fp32 -> bf16 transpose (WT[n][k] = W[k][n]) ----
__global__ __launch_bounds__(256) void tr_k(const float* __restrict__ W,
                                            u16* __restrict__ WT) {
  __shared__ float tile[32][33];
  const int bx = blockIdx.x, by = blockIdx.y;
  const int tx = threadIdx.x & 31, ty = threadIdx.x >> 5;
#pragma unroll
  for (int i = 0; i < 4; i++)
    tile[ty + i * 8][tx] =
        W[(long)(by * 32 + ty + i * 8) * 1024 + bx * 32 + tx];
  __syncthreads();
#pragma unroll
  for (int i = 0; i < 4; i++)
    WT[(long)(bx * 32 + ty + i * 8) * 1024 + by * 32 + tx] =
        f2b(tile[tx][ty + i * 8]);
}

// ---------------- 128x128x32 bf16 MFMA GEMM (m97 structure + T1 swizzle) ---
template <bool RELU, int OMODE>
__global__ __launch_bounds__(256, 2) void gemm_k(
    const u16* __restrict__ A, const u16* __restrict__ BT,
    const float* __restrict__ bias, float scale, float* __restrict__ Cf,
    u16* __restrict__ Cb, int M, int N, int K) {
  __shared__ u16 As[128 * 32];
  __shared__ u16 Bs[128 * 32];
  const int nwg = gridDim.x * gridDim.y;
  const int bid = blockIdx.x + blockIdx.y * gridDim.x;
  const int swz = (bid & 7) * (nwg >> 3) + (bid >> 3);
  const int bxi = swz % gridDim.x, byi = swz / gridDim.x;
  const int t = threadIdx.x;
  const int l = t & 63, w = t >> 6;
  const int lr = l & 15, lg = l >> 4;
  const int wr = (w >> 1) * 64, wc = (w & 1) * 64;
  const long bm = (long)byi * 128, bn = (long)bxi * 128;
  const int srow = l >> 2;
  const int scol = (l & 3) * 8;
  const u16* Ag0 = A + (bm + w * 32 + srow) * (long)K + scol;
  const u16* Ag1 = A + (bm + w * 32 + 16 + srow) * (long)K + scol;
  const u16* Bg0 = BT + (bn + w * 32 + srow) * (long)K + scol;
  const u16* Bg1 = BT + (bn + w * 32 + 16 + srow) * (long)K + scol;
  u16* Al0 = As + w * 1024;
  u16* Al1 = As + w * 1024 + 512;
  u16* Bl0 = Bs + w * 1024;
  u16* Bl1 = Bs + w * 1024 + 512;
  f32x4 acc[4][4] = {};
  for (int k0 = 0; k0 < K; k0 += 32) {
    GLDS16(Ag0 + k0, Al0);
    GLDS16(Ag1 + k0, Al1);
    GLDS16(Bg0 + k0, Bl0);
    GLDS16(Bg1 + k0, Bl1);
    __syncthreads();
    short8 af[4], bf[4];
#pragma unroll
    for (int i = 0; i < 4; i++)
      af[i] = *(const short8*)&As[(wr + i * 16 + lr) * 32 + lg * 8];
#pragma unroll
    for (int i = 0; i < 4; i++)
      bf[i] = *(const short8*)&Bs[(wc + i * 16 + lr) * 32 + lg * 8];
#pragma unroll
    for (int i = 0; i < 4; i++)
#pragma unroll
      for (int j = 0; j < 4; j++)
        acc[i][j] = __builtin_amdgcn_mfma_f32_16x16x32_bf16(af[i], bf[j],
                                                            acc[i][j], 0, 0, 0);
    __syncthreads();
  }
#pragma unroll
  for (int i = 0; i < 4; i++)
#pragma unroll
    for (int j = 0; j < 4; j++) {
      long col = bn + wc + j * 16 + lr;
      float bv = bias[col];
      if (OMODE == 2) {
        long row0 = bm + wr + i * 16 + lg * 4;
        long b = row0 >> 11, l0 = row0 & 2047;
        u16x4 ov;
#pragma unroll
        for (int r = 0; r < 4; r++) {
          float v2 = (acc[i][j][r] + bv) * scale;
          if (RELU) v2 = fmaxf(v2, 0.f);
          ov[r] = f2b(v2);
        }
        *(u16x4*)(Cb + (b * 1024 + col) * 2048 + l0) = ov;
      } else {
#pragma unroll
        for (int r = 0; r < 4; r++) {
          long row = bm + wr + i * 16 + lg * 4 + r;
          float v2 = (acc[i][j][r] + bv) * scale;
          if (RELU) v2 = fmaxf(v2, 0.f);
          if (OMODE == 1)
            Cb[row * N + col] = f2b(v2);
          else
            Cf[row * N + col] = v2;
        }
      }
    }
}

// ---------------- flash attention v4: swapped QK^T, lane-local softmax -----
// 8 waves x 16 q rows. s = mfma(K,Q) -> lane holds q=lr, kv=jc*16+lg*4+r.
// Deferred row-sum (per-lane partials), bpermute P-exchange (no Pw LDS),
// K/V double-buffered LDS -> single barrier per tile. Base-2 softmax
// (Q pre-scaled by log2(e)/sqrt(DH)). T13 defer-max thr=8.
__global__ __launch_bounds__(512, 4) void flash_k(const u16* __restrict__ Q,
                                                  const u16* __restrict__ Kb,
                                                  const u16* __restrict__ VT,
                                                  float* __restrict__ ctx) {
  __shared__ u16 Ks[2][64][136];   // K tile [kv][d], dbuf
  __shared__ u16 VTs[2][128][72];  // V^T tile [d][kv], dbuf
  const int nwg = gridDim.x * gridDim.y;
  const int bid = blockIdx.x + blockIdx.y * gridDim.x;
  const int swz = (bid & 7) * (nwg >> 3) + (bid >> 3);
  const int bxi = swz % gridDim.x, byi = swz / gridDim.x;
  const int t = threadIdx.x;
  const int l = t & 63, w = t >> 6;
  const int lr = l & 15, lg = l >> 4;
  const int b = byi >> 3, h = byi & 7;
  const long kbase = ((long)b * LL) * DD + h * DHH;
  const long vtbase = ((long)(b * 8 + h) * DHH) * LL;
  const int q0 = bxi * 128;

  short8 qf[4];
  {
    const u16* qp = Q + kbase + (long)(q0 + w * 16 + lr) * DD + lg * 8;
#pragma unroll
    for (int c = 0; c < 4; c++) qf[c] = *(const short8*)(qp + c * 32);
  }
  f32x4 oacc[8] = {};
  float mprev = -1e30f;  // running max for q = lr (base-2 domain)
  float lsum = 0.f;      // per-lane PARTIAL row sum (this lane's 16 kv slots)

  const int krow = t >> 3, kcol = (t & 7) * 16;
  const int vrow = t >> 2, vcol = (t & 3) * 16;
  u32x4 kr0, kr1, vr0, vr1;
  {  // stage tile 0 into buf 0
    const u16* kp = Kb + kbase + (long)krow * DD + kcol;
    kr0 = *(const u32x4*)(kp);
    kr1 = *(const u32x4*)(kp + 8);
    const u16* vp = VT + vtbase + (long)vrow * LL + vcol;
    vr0 = *(const u32x4*)(vp);
    vr1 = *(const u32x4*)(vp + 8);
    *(u32x4*)&Ks[0][krow][kcol] = kr0;
    *(u32x4*)&Ks[0][krow][kcol + 8] = kr1;
    *(u32x4*)&VTs[0][vrow][vcol] = vr0;
    *(u32x4*)&VTs[0][vrow][vcol + 8] = vr1;
  }
  const int NT = LL / 64;
  for (int it = 0; it < NT; ++it) {
    const int cur = it & 1;
    if (it + 1 < NT) {  // T14: issue next tile's loads before the barrier
      const u16* kp = Kb + kbase + (long)((it + 1) * 64 + krow) * DD + kcol;
      kr0 = *(const u32x4*)(kp);
      kr1 = *(const u32x4*)(kp + 8);
      const u16* vp = VT + vtbase + (long)vrow * LL + (it + 1) * 64 + vcol;
      vr0 = *(const u32x4*)(vp);
      vr1 = *(const u32x4*)(vp + 8);
    }
    __syncthreads();  // buf[cur] writes visible; everyone done with buf[cur^1]

    // QK^T swapped: s[jc] holds S^T tile jc: lane -> q=lr, kv=jc*16+lg*4+r
    f32x4 s[4] = {};
#pragma unroll
    for (int jc = 0; jc < 4; jc++)
#pragma unroll
      for (int c = 0; c < 4; c++) {
        short8 kf = *(const short8*)&Ks[cur][jc * 16 + lr][c * 32 + lg * 8];
        s[jc] =
            __builtin_amdgcn_mfma_f32_16x16x32_bf16(kf, qf[c], s[jc], 0, 0, 0);
      }

    // in-lane tile max (16 vals) + 2 shfls across lg groups
    float mx = fmaxf(fmaxf(s[0][0], s[0][1]), fmaxf(s[0][2], s[0][3]));
#pragma unroll
    for (int jc = 1; jc < 4; jc++)
      mx = fmaxf(mx, fmaxf(fmaxf(s[jc][0], s[jc][1]),
                           fmaxf(s[jc][2], s[jc][3])));
    mx = fmaxf(mx, __shfl_xor(mx, 16, 64));
    mx = fmaxf(mx, __shfl_xor(mx, 32, 64));

    // T13 defer-max rescale (rare)
    if (__any((int)(mx > mprev + 8.f))) {
      float mn = fmaxf(mprev, mx);
      float alpha = exp2_fast(mprev - mn);
      mprev = mn;
      lsum *= alpha;
      float ar[4];
#pragma unroll
      for (int r = 0; r < 4; r++) ar[r] = __shfl(alpha, lg * 4 + r, 64);
#pragma unroll
      for (int d8 = 0; d8 < 8; d8++)
#pragma unroll
        for (int r = 0; r < 4; r++) oacc[d8][r] *= ar[r];
    }

    // p = 2^(s - mprev); partial sum in-lane; pack bf16 pairs (consec kv)
    u32 pk2[4][2];
    float ladd = 0.f;
#pragma unroll
    for (int jc = 0; jc < 4; jc++) {
      float p0 = exp2_fast(s[jc][0] - mprev);
      float p1 = exp2_fast(s[jc][1] - mprev);
      float p2 = exp2_fast(s[jc][2] - mprev);
      float p3 = exp2_fast(s[jc][3] - mprev);
      ladd += (p0 + p1) + (p2 + p3);
      pk2[jc][0] = packbf(p0, p1);
      pk2[jc][1] = packbf(p2, p3);
    }
    lsum += ladd;

    // P exchange -> A-frag: af u32 m of (lr,lg) at half kk comes from
    // src lane lr+16*((lg&1)*2+(m>>1)), register pk2[2kk+(lg>>1)][m&1]
    short8 pf[2];
#pragma unroll
    for (int kk = 0; kk < 2; kk++) {
      u32x4 afv;
#pragma unroll
      for (int m = 0; m < 4; m++) {
        int srcl = lr + ((((lg & 1) << 1) + (m >> 1)) << 4);
        u32 a0 = bperm(srcl, pk2[2 * kk][m & 1]);
        u32 a1 = bperm(srcl, pk2[2 * kk + 1][m & 1]);
        afv[m] = (lg >> 1) ? a1 : a0;
      }
      pf[kk] = __builtin_bit_cast(short8, afv);
    }

    // PV: oacc[d8] += P(kk) x V(kk)
#pragma unroll
    for (int kk = 0; kk < 2; kk++)
#pragma unroll
      for (int d8 = 0; d8 < 8; d8++) {
        short8 vf = *(const short8*)&VTs[cur][d8 * 16 + lr][kk * 32 + lg * 8];
        oacc[d8] =
            __builtin_amdgcn_mfma_f32_16x16x32_bf16(pf[kk], vf, oacc[d8], 0,
                                                    0, 0);
      }

    if (it + 1 < NT) {  // write prefetched tile into the other buffer
      *(u32x4*)&Ks[cur ^ 1][krow][kcol] = kr0;
      *(u32x4*)&Ks[cur ^ 1][krow][kcol + 8] = kr1;
      *(u32x4*)&VTs[cur ^ 1][vrow][vcol] = vr0;
      *(u32x4*)&VTs[cur ^ 1][vrow][vcol + 8] = vr1;
    }
  }

  // finish row sums: reduce partials across lg groups, broadcast to C rows
  lsum += __shfl_xor(lsum, 16, 64);
  lsum += __shfl_xor(lsum, 32, 64);
#pragma unroll
  for (int r = 0; r < 4; r++) {
    float inv = 1.f / __shfl(lsum, lg * 4 + r, 64);
    float* cp = ctx + kbase + (long)(q0 + w * 16 + lg * 4 + r) * DD;
#pragma unroll
    for (int d8 = 0; d8 < 8; d8++) cp[d8 * 16 + lr] = oacc[d8][r] * inv;
  }
}

// ---------------- residual + layernorm; writes fp32 and/or bf16 ----------
__global__ __launch_bounds__(256) void ln_k(const float* __restrict__ X,
                                            const float* __restrict__ R,
                                            const float* __restrict__ gamma,
                                            const float* __restrict__ beta,
                                            float* __restrict__ Hf,
                                            u16* __restrict__ Hb) {
  const int row = blockIdx.x, t = threadIdx.x;
  const long off = (long)row * DD + t * 4;
  f32x4 v = *(const f32x4*)(X + off);
  f32x4 rv = *(const f32x4*)(R + off);
#pragma unroll
  for (int i = 0; i < 4; i++) v[i] += rv[i];
  float s = v[0] + v[1] + v[2] + v[3];
  float q = v[0] * v[0] + v[1] * v[1] + v[2] * v[2] + v[3] * v[3];
#pragma unroll
  for (int m = 32; m >= 1; m >>= 1) {
    s += __shfl_xor(s, m, 64);
    q += __shfl_xor(q, m, 64);
  }
  __shared__ float red[8];
  if ((t & 63) == 0) {
    red[t >> 6] = s;
    red[4 + (t >> 6)] = q;
  }
  __syncthreads();
  s = red[0] + red[1] + red[2] + red[3];
  q = red[4] + red[5] + red[6] + red[7];
  const float mean = s * (1.f / 1024.f);
  const float var = q * (1.f / 1024.f) - mean * mean;
  const float rstd = rsqrtf(var + 1e-12f);
  f32x4 g = *(const f32x4*)(gamma + t * 4);
  f32x4 be = *(const f32x4*)(beta + t * 4);
  f32x4 o;
#pragma unroll
  for (int i = 0; i < 4; i++) o[i] = g[i] * (v[i] - mean) * rstd + be[i];
  if (Hf) *(f32x4*)(Hf + off) = o;
  if (Hb) {
    u16x4 ob;
#pragma unroll
    for (int i = 0; i < 4; i++) ob[i] = f2b(o[i]);
    *(u16x4*)(Hb + off) = ob;
  }
}

// ---------------- c2: row dot wc2 + relu -> cvec[row] ----------------
__global__ __launch_bounds__(256) void c2_k(const u16* __restrict__ C,
                                            const float* __restrict__ wc2,
                                            const float* __restrict__ bc2,
                                            float* __restrict__ cvec) {
  const int row = blockIdx.x, t = threadIdx.x;
  u16x4 cv = *(const u16x4*)(C + (long)row * DD + t * 4);
  f32x4 wv = *(const f32x4*)(wc2 + t * 4);
  float s = b2f(cv[0]) * wv[0] + b2f(cv[1]) * wv[1] + b2f(cv[2]) * wv[2] +
            b2f(cv[3]) * wv[3];
#pragma unroll
  for (int m = 32; m >= 1; m >>= 1) s += __shfl_xor(s, m, 64);
  __shared__ float red[4];
  if ((t & 63) == 0) red[t >> 6] = s;
  __syncthreads();
  if (t == 0)
    cvec[row] = fmaxf(red[0] + red[1] + red[2] + red[3] + bc2[0], 0.f);
}

// ---------------- small [4,Lr]@[Lr,N] GEMM: split-K partials + reduce -----
__global__ __launch_bounds__(256) void smm_part(const float* __restrict__ Cin,
                                                const float* __restrict__ W,
                                                float* __restrict__ P, int Lr,
                                                int N, int SL) {
  const int j = blockIdx.x * 256 + threadIdx.x;
  const int l0 = blockIdx.y * SL;
  float a0 = 0, a1 = 0, a2 = 0, a3 = 0;
  for (int ll = l0; ll < l0 + SL; ll++) {
    float wv = W[(long)ll * N + j];
    a0 += Cin[ll] * wv;
    a1 += Cin[Lr + ll] * wv;
    a2 += Cin[2 * Lr + ll] * wv;
    a3 += Cin[3 * Lr + ll] * wv;
  }
  float* Pp = P + ((long)blockIdx.y * 4) * N + j;
  Pp[0] = a0;
  Pp[N] = a1;
  Pp[2 * N] = a2;
  Pp[3 * N] = a3;
}

template <bool RELU>
__global__ __launch_bounds__(256) void smm_red(const float* __restrict__ P,
                                               const float* __restrict__ bias,
                                               float* __restrict__ Out, int N,
                                               int S) {
  const int j = blockIdx.x * 256 + threadIdx.x;
#pragma unroll
  for (int b = 0; b < 4; b++) {
    float a = 0;
    for (int s = 0; s < S; s++) a += P[((long)s * 4 + b) * N + j];
    a += bias[j];
    if (RELU) a = fmaxf(a, 0.f);
    Out[(long)b * N + j] = a;
  }
}

extern "C" void kernel_launch(void* const* d_in, const int* in_sizes, int n_in,
                              void* d_out, int out_size, void* d_ws,
                              size_t ws_size, hipStream_t stream) {
  (void)in_sizes; (void)n_in; (void)out_size; (void)ws_size;
  const float* x = (const float*)d_in[0];
  const float* wq = (const float*)d_in[1];
  const float* bq = (const float*)d_in[2];
  const float* wk = (const float*)d_in[3];
  const float* bk = (const float*)d_in[4];
  const float* wv = (const float*)d_in[5];
  const float* bv = (const float*)d_in[6];
  const float* gamma = (const float*)d_in[7];
  const float* beta = (const float*)d_in[8];
  const float* wff = (const float*)d_in[9];
  const float* bff = (const float*)d_in[10];
  const float* wc1 = (const float*)d_in[11];
  const float* bc1 = (const float*)d_in[12];
  const float* wc2 = (const float*)d_in[13];
  const float* bc2 = (const float*)d_in[14];
  const float* wl1 = (const float*)d_in[15];
  const float* bl1 = (const float*)d_in[16];
  const float* wl2 = (const float*)d_in[17];
  const float* bl2 = (const float*)d_in[18];

  char* wsp = (char*)d_ws;
  size_t off = 0;
  auto take = [&](size_t bytes) -> char* {
    char* p = wsp + off;
    off += (bytes + 255) & ~(size_t)255;
    return p;
  };
  u16* xb = (u16*)take((size_t)8192 * 1024 * 2);
  u16* wqT = (u16*)take((size_t)1024 * 1024 * 2);
  u16* wkT = (u16*)take((size_t)1024 * 1024 * 2);
  u16* wvT = (u16*)take((size_t)1024 * 1024 * 2);
  u16* wffT = (u16*)take((size_t)1024 * 1024 * 2);
  u16* wc1T = (u16*)take((size_t)1024 * 1024 * 2);
  u16* qb = (u16*)take((size_t)8192 * 1024 * 2);
  u16* kbuf = (u16*)take((size_t)8192 * 1024 * 2);
  u16* vT = (u16*)take((size_t)8192 * 1024 * 2);
  float* ctxb = (float*)take((size_t)8192 * 1024 * 4);
  float* h1f = (float*)take((size_t)8192 * 1024 * 4);
  float* cvec = (float*)take(8192 * 4);
  float* c3 = (float*)take(8192 * 4);
  float* P1 = (float*)take((size_t)16 * 4 * 2048 * 4);
  float* P2 = (float*)take((size_t)16 * 4 * 256 * 4);
  u16* h1b = qb;
  u16* h2b = kbuf;
  u16* cb = vT;
  float* ff = ctxb;

  cvt_k<<<8192, 256, 0, stream>>>(x, xb, (long)8192 * 1024);
  dim3 trg(32, 32);
  tr_k<<<trg, 256, 0, stream>>>(wq, wqT);
  tr_k<<<trg, 256, 0, stream>>>(wk, wkT);
  tr_k<<<trg, 256, 0, stream>>>(wv, wvT);
  tr_k<<<trg, 256, 0, stream>>>(wff, wffT);
  tr_k<<<trg, 256, 0, stream>>>(wc1, wc1T);

  dim3 gg(8, 64);
  // Q scale folds 1/sqrt(128) * log2(e) for base-2 softmax
  gemm_k<false, 1><<<gg, 256, 0, stream>>>(
      xb, wqT, bq, 0.12751743f, nullptr, qb, 8192, 1024, 1024);
  gemm_k<false, 1><<<gg, 256, 0, stream>>>(xb, wkT, bk, 1.f, nullptr, kbuf,
                                           8192, 1024, 1024);
  gemm_k<false, 2><<<gg, 256, 0, stream>>>(xb, wvT, bv, 1.f, nullptr, vT,
                                           8192, 1024, 1024);
  flash_k<<<dim3(16, 32), 512, 0, stream>>>(qb, kbuf, vT, ctxb);
  ln_k<<<8192, 256, 0, stream>>>(x, ctxb, gamma, beta, h1f, h1b);
  gemm_k<true, 0><<<gg, 256, 0, stream>>>(h1b, wffT, bff, 1.f, ff, nullptr,
                                          8192, 1024, 1024);
  ln_k<<<8192, 256, 0, stream>>>(h1f, ff, gamma, beta, nullptr, h2b);
  gemm_k<true, 1><<<gg, 256, 0, stream>>>(h2b, wc1T, bc1, 1.f, nullptr, cb,
                                          8192, 1024, 1024);
  c2_k<<<8192, 256, 0, stream>>>(cb, wc2, bc2, cvec);
  smm_part<<<dim3(8, 16), 256, 0, stream>>>(cvec, wl1, P1, 2048, 2048, 128);
  smm_red<true><<<8, 256, 0, stream>>>(P1, bl1, c3, 2048, 16);
  smm_part<<<dim3(1, 16), 256, 0, stream>>>(c3, wl2, P2, 2048, 256, 128);
  smm_red<false><<<1, 256, 0, stream>>>(P2, bl2, (float*)d_out, 256, 16);
}